// Round 16
// baseline (257.116 us; speedup 1.0000x reference)
//
#include <hip/hip_runtime.h>
#include <stdint.h>
#include <math.h>

#define BB 8
#define SEQ 2048
#define CDIM 384
#define NH 6
#define HD 64
#define QKVN 1152

typedef __attribute__((ext_vector_type(8))) __bf16 bf16x8;
typedef __attribute__((ext_vector_type(4))) __bf16 bf16x4;
typedef __attribute__((ext_vector_type(4))) float f32x4;
typedef __attribute__((ext_vector_type(4))) unsigned short ushort4v;

__device__ __forceinline__ unsigned short f2bf(float f) {
  unsigned int u = __float_as_uint(f);
  u += 0x7fffu + ((u >> 16) & 1u);
  return (unsigned short)(u >> 16);
}

// fp32 -> bf16 conversion, 4 elems/thread
__global__ void k_convert(const float* __restrict__ src, unsigned short* __restrict__ dst, int n4) {
  int i = blockIdx.x * blockDim.x + threadIdx.x;
  if (i >= n4) return;
  float4 f = reinterpret_cast<const float4*>(src)[i];
  ushort4v u;
  u.x = f2bf(f.x); u.y = f2bf(f.y); u.z = f2bf(f.z); u.w = f2bf(f.w);
  reinterpret_cast<ushort4v*>(dst)[i] = u;
}

__device__ __forceinline__ void gload_lds16(const unsigned short* g, unsigned short* l) {
  __builtin_amdgcn_global_load_lds((const __attribute__((address_space(1))) void*)g,
                                   (__attribute__((address_space(3))) void*)l, 16, 0, 0);
}

// C[M,Nc] = A[M,K] * Bm[Nc,K]^T   (both row-major bf16, K contiguous; m97 structure)
template<int OUT_F32>
__global__ __launch_bounds__(256, 2) void k_gemm_bt(
    const unsigned short* __restrict__ A, const unsigned short* __restrict__ Bm,
    unsigned short* __restrict__ Cb, float* __restrict__ Cf,
    const float* __restrict__ bias, int M, int Nc, int K)
{
  __shared__ unsigned short lA[128 * 32];
  __shared__ unsigned short lB[128 * 32];
  const int t = threadIdx.x;
  const int w = t >> 6, l = t & 63;
  const int wr = w >> 1, wc = w & 1;
  const int row0 = blockIdx.x * 128, col0 = blockIdx.y * 128;
  const f32x4 vzero = {0.f, 0.f, 0.f, 0.f};
  f32x4 acc[4][4];
#pragma unroll
  for (int m = 0; m < 4; ++m)
#pragma unroll
    for (int n = 0; n < 4; ++n) acc[m][n] = vzero;

  const int srow = w * 16 + (l >> 2);
  const int scol = (l & 3) * 8;
  const int lr = l & 15, kc = (l >> 4) * 8;

  for (int k0 = 0; k0 < K; k0 += 32) {
#pragma unroll
    for (int r = 0; r < 2; ++r) {
      gload_lds16(A + (size_t)(row0 + r * 64 + srow) * K + k0 + scol,
                  &lA[(r * 64 + srow) * 32 + scol]);
      gload_lds16(Bm + (size_t)(col0 + r * 64 + srow) * K + k0 + scol,
                  &lB[(r * 64 + srow) * 32 + scol]);
    }
    __syncthreads();
    bf16x8 af[4], bfr[4];
#pragma unroll
    for (int m = 0; m < 4; ++m)
      af[m] = *(const bf16x8*)&lA[(wr * 64 + m * 16 + lr) * 32 + kc];
#pragma unroll
    for (int n = 0; n < 4; ++n)
      bfr[n] = *(const bf16x8*)&lB[(wc * 64 + n * 16 + lr) * 32 + kc];
#pragma unroll
    for (int m = 0; m < 4; ++m)
#pragma unroll
      for (int n = 0; n < 4; ++n)
        acc[m][n] = __builtin_amdgcn_mfma_f32_16x16x32_bf16(af[m], bfr[n], acc[m][n], 0, 0, 0);
    __syncthreads();
  }

#pragma unroll
  for (int m = 0; m < 4; ++m) {
    const int row = row0 + wr * 64 + m * 16 + (l >> 4) * 4;
#pragma unroll
    for (int n = 0; n < 4; ++n) {
      const int col = col0 + wc * 64 + n * 16 + (l & 15);
      if (OUT_F32) {
        const float bv = bias[col];
#pragma unroll
        for (int j = 0; j < 4; ++j)
          Cf[(size_t)(row + j) * Nc + col] = acc[m][n][j] + bv;
      } else {
#pragma unroll
        for (int j = 0; j < 4; ++j)
          Cb[(size_t)(row + j) * Nc + col] = f2bf(acc[m][n][j]);
      }
    }
  }
}

// V slice of qkv (b,n,768 + h*64 + d) -> VT[(b*H+h), d, n]  (bf16)
__global__ void k_vtrans(const unsigned short* __restrict__ qkv, unsigned short* __restrict__ vt)
{
  __shared__ unsigned short tile[64][76];
  const int bh = blockIdx.x;
  const int b = bh / NH, h = bh - b * NH;
  const int n0 = blockIdx.y * 64;
  const int t = threadIdx.x;
  const int rr0 = t >> 4;
  const int c4 = (t & 15) * 4;
  const unsigned short* src = qkv + (size_t)(b * SEQ + n0) * QKVN + 2 * CDIM + h * HD;
#pragma unroll
  for (int rr = 0; rr < 4; ++rr) {
    int n = rr * 16 + rr0;
    ushort4v v = *(const ushort4v*)(src + (size_t)n * QKVN + c4);
    *(ushort4v*)&tile[n][c4] = v;
  }
  __syncthreads();
  unsigned short* dst = vt + (size_t)bh * HD * SEQ + n0;
#pragma unroll
  for (int rr = 0; rr < 4; ++rr) {
    int d = rr * 16 + rr0;
    ushort4v v;
    v.x = tile[c4 + 0][d];
    v.y = tile[c4 + 1][d];
    v.z = tile[c4 + 2][d];
    v.w = tile[c4 + 3][d];
    *(ushort4v*)(dst + (size_t)d * SEQ + c4) = v;
  }
}

// Flash attention v16: r15 + DEFERRED-PV pipeline (T15 adapted). PV(t-1) runs
// right after QK(t) as a pure-MFMA cluster, independent of softmax(t)'s VALU
// chain -> MFMA pipe grinds PV while VALU does mask/max/exp2. P-fragments
// persist in regs across iterations; V triple-buffered (PV(t-1) reads slot
// t-1 while staging writes slot t+1). Rescale ordering exact: PV(t-1) lands
// while acco/asum are still at scale m(t-1), before al(t) applies.
__global__ __launch_bounds__(256, 3) void k_attn(
    const unsigned short* __restrict__ qkv, const float* __restrict__ mask,
    const unsigned short* __restrict__ vt, unsigned short* __restrict__ aout)
{
  const int bid = blockIdx.x;
  const int b = bid & 7;            // batch -> XCD (768 = 8*96, bijective)
  const int g2 = bid >> 3;          // 0..95
  const int h = g2 % NH;
  const int nt = g2 / NH;           // 0..15
  const int t = threadIdx.x;
  const int w = t >> 6, l = t & 63;
  const int gk = l >> 4, c = l & 15;
  const int q0 = nt * 128 + w * 16;   // tile0; tile1 = q0+64

  __shared__ unsigned short lK[2][4096];
  __shared__ unsigned short lV[3][4096];   // triple-buffered for deferred PV

  const unsigned short* qb0 = qkv + (size_t)(b * SEQ + q0) * QKVN + h * HD;
  const unsigned short* qb1 = qb0 + (size_t)64 * QKVN;
  const unsigned short* kb = qkv + (size_t)(b * SEQ) * QKVN + CDIM + h * HD;
  const unsigned short* vb = vt + (size_t)(b * NH + h) * HD * SEQ;
  const float* mrow0 = mask + ((size_t)b * SEQ + q0 + c) * SEQ + 4 * gk;
  const float* mrow1 = mrow0 + (size_t)64 * SEQ;

  // staging: 256 threads x 16B x 2 issues = 64x64 bf16 tile; source pre-swizzled
  const int trow = t >> 3, tg = t & 7;
  const int glog = tg ^ (trow & 7);
  const size_t kSrc = (size_t)trow * QKVN + glog * 8;
  const size_t vSrc = (size_t)trow * SEQ + glog * 8;
  const int tid8 = t * 8;

  // K fragment ds_read offsets (b128, elems)
  const int fr0 = c * 64 + ((gk) ^ (c & 7)) * 8;
  const int fr1 = c * 64 + ((4 + gk) ^ (c & 7)) * 8;
  // V b64 granule offsets (8B granule g at row c: phys = g ^ (2*(c&7)))
  const int cx2 = 2 * (c & 7);
  const int vg0 = c * 64 + ((gk) ^ cx2) * 4;       // keys 4gk..4gk+3
  const int vg1 = c * 64 + ((4 + gk) ^ cx2) * 4;   // keys 16+4gk..+3
  const int vg2 = c * 64 + ((8 + gk) ^ cx2) * 4;   // keys 32+4gk..+3
  const int vg3 = c * 64 + ((12 + gk) ^ cx2) * 4;  // keys 48+4gk..+3

  // Q as B'-frag (col=q=c, d-chunk gk*8), pre-scaled by rsqrt(D)*log2(e)
  bf16x8 qf00 = *(const bf16x8*)(qb0 + (size_t)c * QKVN + gk * 8);
  bf16x8 qf01 = *(const bf16x8*)(qb0 + (size_t)c * QKVN + 32 + gk * 8);
  bf16x8 qf10 = *(const bf16x8*)(qb1 + (size_t)c * QKVN + gk * 8);
  bf16x8 qf11 = *(const bf16x8*)(qb1 + (size_t)c * QKVN + 32 + gk * 8);
#pragma unroll
  for (int i = 0; i < 8; ++i) {
    qf00[i] = (__bf16)((float)qf00[i] * 0.18033688f);
    qf01[i] = (__bf16)((float)qf01[i] * 0.18033688f);
    qf10[i] = (__bf16)((float)qf10[i] * 0.18033688f);
    qf11[i] = (__bf16)((float)qf11[i] * 0.18033688f);
  }

  const __bf16 one = (__bf16)1.0f;
  const bf16x8 vones = {one, one, one, one, one, one, one, one};
  const f32x4 vzero = {0.f, 0.f, 0.f, 0.f};
  f32x4 acco0[4], acco1[4];
  f32x4 asum0 = vzero, asum1 = vzero;      // rowsum in ACC layout (q=4gk+r)
  float mreg0 = -INFINITY, mreg1 = -INFINITY;
#pragma unroll
  for (int dt = 0; dt < 4; ++dt) { acco0[dt] = vzero; acco1[dt] = vzero; }

  // persisted P-fragments (written at iter t, consumed by PV at iter t+1)
  union PU { unsigned int u[8]; bf16x8 v[2]; };
  PU pu0 = {}, pu1 = {};

  // prologue: stage kt=0 into K-buf 0 and V-slot 0
#pragma unroll
  for (int j = 0; j < 2; ++j) {
    gload_lds16(kb + (size_t)j * 32 * QKVN + kSrc, &lK[0][j * 2048 + tid8]);
    gload_lds16(vb + (size_t)j * 32 * SEQ + vSrc, &lV[0][j * 2048 + tid8]);
  }
  int bufK = 0;
  int vst = 1;   // V slot for staging (t+1)%3
  int vpv = 2;   // V slot holding V(t-1) = (t+2)%3; valid from t>=1

  for (int kt = 0; kt < SEQ; kt += 64) {
    const bool haveNext = (kt + 64 < SEQ);
    __syncthreads();
    if (haveNext) {
#pragma unroll
      for (int j = 0; j < 2; ++j) {
        gload_lds16(kb + (size_t)(kt + 64 + j * 32) * QKVN + kSrc, &lK[bufK ^ 1][j * 2048 + tid8]);
        gload_lds16(vb + (kt + 64) + (size_t)j * 32 * SEQ + vSrc, &lV[vst][j * 2048 + tid8]);
      }
    }

    // mask loads for current tile-pair (L2/L3-warm; latency covered by QK)
    float4 mk0[4], mk1[4];
#pragma unroll
    for (int j = 0; j < 4; ++j) {
      mk0[j] = *(const float4*)(mrow0 + kt + 16 * j);
      mk1[j] = *(const float4*)(mrow1 + kt + 16 * j);
    }

    // QK^T(t) for both tiles, then DEFERRED PV(t-1): the PV cluster is
    // independent of softmax(t), so the MFMA pipe stays busy under the
    // VALU chain that follows.
    f32x4 s0[4], s1[4];
    __builtin_amdgcn_s_setprio(1);
#pragma unroll
    for (int j = 0; j < 4; ++j) {
      bf16x8 kfa = *(const bf16x8*)&lK[bufK][j * 1024 + fr0];
      bf16x8 kfb = *(const bf16x8*)&lK[bufK][j * 1024 + fr1];
      s0[j] = __builtin_amdgcn_mfma_f32_16x16x32_bf16(kfa, qf00, vzero, 0, 0, 0);
      s0[j] = __builtin_amdgcn_mfma_f32_16x16x32_bf16(kfb, qf01, s0[j], 0, 0, 0);
      s1[j] = __builtin_amdgcn_mfma_f32_16x16x32_bf16(kfa, qf10, vzero, 0, 0, 0);
      s1[j] = __builtin_amdgcn_mfma_f32_16x16x32_bf16(kfb, qf11, s1[j], 0, 0, 0);
    }
    if (kt > 0) {
      // acco/asum are at scale m(t-1); P(t-1) matches. Apply before rescale.
      asum0 = __builtin_amdgcn_mfma_f32_16x16x32_bf16(pu0.v[0], vones, asum0, 0, 0, 0);
      asum0 = __builtin_amdgcn_mfma_f32_16x16x32_bf16(pu0.v[1], vones, asum0, 0, 0, 0);
      asum1 = __builtin_amdgcn_mfma_f32_16x16x32_bf16(pu1.v[0], vones, asum1, 0, 0, 0);
      asum1 = __builtin_amdgcn_mfma_f32_16x16x32_bf16(pu1.v[1], vones, asum1, 0, 0, 0);
#pragma unroll
      for (int dt = 0; dt < 4; ++dt) {
        const unsigned short* vrow = &lV[vpv][dt * 1024];
        bf16x4 a0v = *(const bf16x4*)(vrow + vg0);
        bf16x4 a1v = *(const bf16x4*)(vrow + vg1);
        bf16x4 a2v = *(const bf16x4*)(vrow + vg2);
        bf16x4 a3v = *(const bf16x4*)(vrow + vg3);
        bf16x8 vf0 = __builtin_shufflevector(a0v, a1v, 0, 1, 2, 3, 4, 5, 6, 7);
        bf16x8 vf1 = __builtin_shufflevector(a2v, a3v, 0, 1, 2, 3, 4, 5, 6, 7);
        acco0[dt] = __builtin_amdgcn_mfma_f32_16x16x32_bf16(pu0.v[0], vf0, acco0[dt], 0, 0, 0);
        acco0[dt] = __builtin_amdgcn_mfma_f32_16x16x32_bf16(pu0.v[1], vf1, acco0[dt], 0, 0, 0);
        acco1[dt] = __builtin_amdgcn_mfma_f32_16x16x32_bf16(pu1.v[0], vf0, acco1[dt], 0, 0, 0);
        acco1[dt] = __builtin_amdgcn_mfma_f32_16x16x32_bf16(pu1.v[1], vf1, acco1[dt], 0, 0, 0);
      }
    }
    __builtin_amdgcn_s_setprio(0);

    // masked log2-scores in place (two independent chains from here)
#pragma unroll
    for (int j = 0; j < 4; ++j) {
      const float* m0 = (const float*)&mk0[j];
      const float* m1 = (const float*)&mk1[j];
#pragma unroll
      for (int r = 0; r < 4; ++r) {
        s0[j][r] = fmaf(m0[r], -144269.50f, s0[j][r]);
        s1[j][r] = fmaf(m1[r], -144269.50f, s1[j][r]);
      }
    }

    // per-lane max (max3-shaped: 3-ary fmaxf nests fuse to v_max3_f32)
    float a0 = fmaxf(fmaxf(s0[0][0], s0[0][1]), s0[0][2]);
    float b0 = fmaxf(fmaxf(s0[0][3], s0[1][0]), s0[1][1]);
    float d0 = fmaxf(fmaxf(s0[1][2], s0[1][3]), s0[2][0]);
    float e0 = fmaxf(fmaxf(s0[2][1], s0[2][2]), s0[2][3]);
    float f0 = fmaxf(fmaxf(s0[3][0], s0[3][1]), s0[3][2]);
    float tm0 = fmaxf(fmaxf(fmaxf(a0, b0), d0), fmaxf(fmaxf(e0, f0), s0[3][3]));
    float a1 = fmaxf(fmaxf(s1[0][0], s1[0][1]), s1[0][2]);
    float b1 = fmaxf(fmaxf(s1[0][3], s1[1][0]), s1[1][1]);
    float d1 = fmaxf(fmaxf(s1[1][2], s1[1][3]), s1[2][0]);
    float e1 = fmaxf(fmaxf(s1[2][1], s1[2][2]), s1[2][3]);
    float f1 = fmaxf(fmaxf(s1[3][0], s1[3][1]), s1[3][2]);
    float tm1 = fmaxf(fmaxf(fmaxf(a1, b1), d1), fmaxf(fmaxf(e1, f1), s1[3][3]));
    tm0 = fmaxf(tm0, __shfl_xor(tm0, 16));
    tm1 = fmaxf(tm1, __shfl_xor(tm1, 16));
    tm0 = fmaxf(tm0, __shfl_xor(tm0, 32));
    tm1 = fmaxf(tm1, __shfl_xor(tm1, 32));

    // defer-rescale (T13, thr=8 in log2 domain), per tile
    if (__any(tm0 > mreg0 + 8.f)) {
      const float mn = fmaxf(mreg0, tm0);
      const float al = __builtin_amdgcn_exp2f(mreg0 - mn);
      mreg0 = mn;
      float alr[4];
#pragma unroll
      for (int r = 0; r < 4; ++r) alr[r] = __shfl(al, 20 * gk + r);
#pragma unroll
      for (int r = 0; r < 4; ++r) asum0[r] *= alr[r];
#pragma unroll
      for (int dt = 0; dt < 4; ++dt)
#pragma unroll
        for (int r = 0; r < 4; ++r) acco0[dt][r] *= alr[r];
    }
    if (__any(tm1 > mreg1 + 8.f)) {
      const float mn = fmaxf(mreg1, tm1);
      const float al = __builtin_amdgcn_exp2f(mreg1 - mn);
      mreg1 = mn;
      float alr[4];
#pragma unroll
      for (int r = 0; r < 4; ++r) alr[r] = __shfl(al, 20 * gk + r);
#pragma unroll
      for (int r = 0; r < 4; ++r) asum1[r] *= alr[r];
#pragma unroll
      for (int dt = 0; dt < 4; ++dt)
#pragma unroll
        for (int r = 0; r < 4; ++r) acco1[dt][r] *= alr[r];
    }

    // P = exp2(s - m) in place; pack into persisted A-fragments for PV at t+1
#pragma unroll
    for (int j = 0; j < 4; ++j)
#pragma unroll
      for (int r = 0; r < 4; ++r) {
        s0[j][r] = __builtin_amdgcn_exp2f(s0[j][r] - mreg0);
        s1[j][r] = __builtin_amdgcn_exp2f(s1[j][r] - mreg1);
      }
#pragma unroll
    for (int j = 0; j < 4; ++j) {
      asm("v_cvt_pk_bf16_f32 %0, %1, %2" : "=v"(pu0.u[2 * j]) : "v"(s0[j][0]), "v"(s0[j][1]));
      asm("v_cvt_pk_bf16_f32 %0, %1, %2" : "=v"(pu0.u[2 * j + 1]) : "v"(s0[j][2]), "v"(s0[j][3]));
      asm("v_cvt_pk_bf16_f32 %0, %1, %2" : "=v"(pu1.u[2 * j]) : "v"(s1[j][0]), "v"(s1[j][1]));
      asm("v_cvt_pk_bf16_f32 %0, %1, %2" : "=v"(pu1.u[2 * j + 1]) : "v"(s1[j][2]), "v"(s1[j][3]));
    }

    bufK ^= 1;
    vst = (vst == 2) ? 0 : vst + 1;
    vpv = (vpv == 2) ? 0 : vpv + 1;
  }

  // epilogue: final PV for the last tile (V(T-1) sits in slot vpv)
  asum0 = __builtin_amdgcn_mfma_f32_16x16x32_bf16(pu0.v[0], vones, asum0, 0, 0, 0);
  asum0 = __builtin_amdgcn_mfma_f32_16x16x32_bf16(pu0.v[1], vones, asum0, 0, 0, 0);
  asum1 = __builtin_amdgcn_mfma_f32_16x16x32_bf16(pu1.v[0], vones, asum1, 0, 0, 0);
  asum1 = __builtin_amdgcn_mfma_f32_16x16x32_bf16(pu1.v[1], vones, asum1, 0, 0, 0);
#pragma unroll
  for (int dt = 0; dt < 4; ++dt) {
    const unsigned short* vrow = &lV[vpv][dt * 1024];
    bf16x4 a0v = *(const bf16x4*)(vrow + vg0);
    bf16x4 a1v = *(const bf16x4*)(vrow + vg1);
    bf16x4 a2v = *(const bf16x4*)(vrow + vg2);
    bf16x4 a3v = *(const bf16x4*)(vrow + vg3);
    bf16x8 vf0 = __builtin_shufflevector(a0v, a1v, 0, 1, 2, 3, 4, 5, 6, 7);
    bf16x8 vf1 = __builtin_shufflevector(a2v, a3v, 0, 1, 2, 3, 4, 5, 6, 7);
    acco0[dt] = __builtin_amdgcn_mfma_f32_16x16x32_bf16(pu0.v[0], vf0, acco0[dt], 0, 0, 0);
    acco0[dt] = __builtin_amdgcn_mfma_f32_16x16x32_bf16(pu0.v[1], vf1, acco0[dt], 0, 0, 0);
    acco1[dt] = __builtin_amdgcn_mfma_f32_16x16x32_bf16(pu1.v[0], vf0, acco1[dt], 0, 0, 0);
    acco1[dt] = __builtin_amdgcn_mfma_f32_16x16x32_bf16(pu1.v[1], vf1, acco1[dt], 0, 0, 0);
  }

  // normalize + store both tiles (asum already in acc layout: no shfl)
  float inv0[4], inv1[4];
#pragma unroll
  for (int r = 0; r < 4; ++r) {
    inv0[r] = 1.0f / asum0[r];
    inv1[r] = 1.0f / asum1[r];
  }
  unsigned short* ob0 = aout + (size_t)(b * SEQ + q0) * CDIM + h * HD;
  unsigned short* ob1 = ob0 + (size_t)64 * CDIM;
#pragma unroll
  for (int r = 0; r < 4; ++r)
#pragma unroll
    for (int dt = 0; dt < 4; ++dt) {
      ob0[(size_t)(4 * gk + r) * CDIM + dt * 16 + c] = f2bf(acco0[dt][r] * inv0[r]);
      ob1[(size_t)(4 * gk + r) * CDIM + dt * 16 + c] = f2bf(acco1[dt][r] * inv1[r]);
    }
}

extern "C" void kernel_launch(void* const* d_in, const int* in_sizes, int n_in,
                              void* d_out, int out_size, void* d_ws, size_t ws_size,
                              hipStream_t stream) {
  (void)in_sizes; (void)n_in; (void)out_size; (void)ws_size;
  const float* x      = (const float*)d_in[0];
  const float* mask   = (const float*)d_in[2];
  const float* qkv_w  = (const float*)d_in[3];
  const float* proj_w = (const float*)d_in[4];
  const float* proj_b = (const float*)d_in[5];
  float* out = (float*)d_out;
  char* ws = (char*)d_ws;

  unsigned short* xb    = (unsigned short*)(ws + 0);         // x bf16:      12,582,912
  unsigned short* wqb   = (unsigned short*)(ws + 12582912);  // qkv_w bf16:     884,736
  unsigned short* wpb   = (unsigned short*)(ws + 13467648);  // proj_w bf16:    294,912
  unsigned short* qkvb  = (unsigned short*)(ws + 13762560);  // qkv bf16:    37,748,736
  unsigned short* vtb   = (unsigned short*)(ws + 51511296);  // V^T bf16:    12,582,912
  unsigned short* aoutb = (unsigned short*)(ws + 64094208);  // attn out:    12,582,912

  k_convert<<<6144, 256, 0, stream>>>(x, xb, 1572864);
  k_convert<<<432, 256, 0, stream>>>(qkv_w, wqb, 110592);
  k_convert<<<144, 256, 0, stream>>>(proj_w, wpb, 36864);
  k_gemm_bt<0><<<dim3(128, 9), 256, 0, stream>>>(xb, wqb, qkvb, nullptr, nullptr, 16384, 1152, 384);
  k_vtrans<<<dim3(48, 32), 256, 0, stream>>>(qkvb, vtb);
  k_attn<<<768, 256, 0, stream>>>(qkvb, mask, vtb, aoutb);
  k_gemm_bt<1><<<dim3(128, 3), 256, 0, stream>>>(aoutb, wpb, nullptr, out, proj_b, 16384, 384, 384);
}

// Round 17
// 178.267 us; speedup vs baseline: 1.4423x; 1.4423x over previous
//
#include <hip/hip_runtime.h>
#include <stdint.h>
#include <math.h>

#define BB 8
#define SEQ 2048
#define CDIM 384
#define NH 6
#define HD 64
#define QKVN 1152

typedef __attribute__((ext_vector_type(8))) __bf16 bf16x8;
typedef __attribute__((ext_vector_type(4))) float f32x4;
typedef __attribute__((ext_vector_type(16))) float f32x16;
typedef __attribute__((ext_vector_type(4))) unsigned short ushort4v;

__device__ __forceinline__ unsigned short f2bf(float f) {
  unsigned int u = __float_as_uint(f);
  u += 0x7fffu + ((u >> 16) & 1u);
  return (unsigned short)(u >> 16);
}

// fp32 -> bf16 conversion, 4 elems/thread
__global__ void k_convert(const float* __restrict__ src, unsigned short* __restrict__ dst, int n4) {
  int i = blockIdx.x * blockDim.x + threadIdx.x;
  if (i >= n4) return;
  float4 f = reinterpret_cast<const float4*>(src)[i];
  ushort4v u;
  u.x = f2bf(f.x); u.y = f2bf(f.y); u.z = f2bf(f.z); u.w = f2bf(f.w);
  reinterpret_cast<ushort4v*>(dst)[i] = u;
}

__device__ __forceinline__ void gload_lds16(const unsigned short* g, unsigned short* l) {
  __builtin_amdgcn_global_load_lds((const __attribute__((address_space(1))) void*)g,
                                   (__attribute__((address_space(3))) void*)l, 16, 0, 0);
}

// C[M,Nc] = A[M,K] * Bm[Nc,K]^T   (both row-major bf16, K contiguous; m97 structure)
template<int OUT_F32>
__global__ __launch_bounds__(256, 2) void k_gemm_bt(
    const unsigned short* __restrict__ A, const unsigned short* __restrict__ Bm,
    unsigned short* __restrict__ Cb, float* __restrict__ Cf,
    const float* __restrict__ bias, int M, int Nc, int K)
{
  __shared__ unsigned short lA[128 * 32];
  __shared__ unsigned short lB[128 * 32];
  const int t = threadIdx.x;
  const int w = t >> 6, l = t & 63;
  const int wr = w >> 1, wc = w & 1;
  const int row0 = blockIdx.x * 128, col0 = blockIdx.y * 128;
  const f32x4 vzero = {0.f, 0.f, 0.f, 0.f};
  f32x4 acc[4][4];
#pragma unroll
  for (int m = 0; m < 4; ++m)
#pragma unroll
    for (int n = 0; n < 4; ++n) acc[m][n] = vzero;

  const int srow = w * 16 + (l >> 2);
  const int scol = (l & 3) * 8;
  const int lr = l & 15, kc = (l >> 4) * 8;

  for (int k0 = 0; k0 < K; k0 += 32) {
#pragma unroll
    for (int r = 0; r < 2; ++r) {
      gload_lds16(A + (size_t)(row0 + r * 64 + srow) * K + k0 + scol,
                  &lA[(r * 64 + srow) * 32 + scol]);
      gload_lds16(Bm + (size_t)(col0 + r * 64 + srow) * K + k0 + scol,
                  &lB[(r * 64 + srow) * 32 + scol]);
    }
    __syncthreads();
    bf16x8 af[4], bfr[4];
#pragma unroll
    for (int m = 0; m < 4; ++m)
      af[m] = *(const bf16x8*)&lA[(wr * 64 + m * 16 + lr) * 32 + kc];
#pragma unroll
    for (int n = 0; n < 4; ++n)
      bfr[n] = *(const bf16x8*)&lB[(wc * 64 + n * 16 + lr) * 32 + kc];
#pragma unroll
    for (int m = 0; m < 4; ++m)
#pragma unroll
      for (int n = 0; n < 4; ++n)
        acc[m][n] = __builtin_amdgcn_mfma_f32_16x16x32_bf16(af[m], bfr[n], acc[m][n], 0, 0, 0);
    __syncthreads();
  }

#pragma unroll
  for (int m = 0; m < 4; ++m) {
    const int row = row0 + wr * 64 + m * 16 + (l >> 4) * 4;
#pragma unroll
    for (int n = 0; n < 4; ++n) {
      const int col = col0 + wc * 64 + n * 16 + (l & 15);
      if (OUT_F32) {
        const float bv = bias[col];
#pragma unroll
        for (int j = 0; j < 4; ++j)
          Cf[(size_t)(row + j) * Nc + col] = acc[m][n][j] + bv;
      } else {
#pragma unroll
        for (int j = 0; j < 4; ++j)
          Cb[(size_t)(row + j) * Nc + col] = f2bf(acc[m][n][j]);
      }
    }
  }
}

// V slice of qkv (b,n,768 + h*64 + d) -> VT[(b*H+h), d, n]  (bf16)
__global__ void k_vtrans(const unsigned short* __restrict__ qkv, unsigned short* __restrict__ vt)
{
  __shared__ unsigned short tile[64][76];
  const int bh = blockIdx.x;
  const int b = bh / NH, h = bh - b * NH;
  const int n0 = blockIdx.y * 64;
  const int t = threadIdx.x;
  const int rr0 = t >> 4;
  const int c4 = (t & 15) * 4;
  const unsigned short* src = qkv + (size_t)(b * SEQ + n0) * QKVN + 2 * CDIM + h * HD;
#pragma unroll
  for (int rr = 0; rr < 4; ++rr) {
    int n = rr * 16 + rr0;
    ushort4v v = *(const ushort4v*)(src + (size_t)n * QKVN + c4);
    *(ushort4v*)&tile[n][c4] = v;
  }
  __syncthreads();
  unsigned short* dst = vt + (size_t)bh * HD * SEQ + n0;
#pragma unroll
  for (int rr = 0; rr < 4; ++rr) {
    int d = rr * 16 + rr0;
    ushort4v v;
    v.x = tile[c4 + 0][d];
    v.y = tile[c4 + 1][d];
    v.z = tile[c4 + 2][d];
    v.w = tile[c4 + 3][d];
    *(ushort4v*)(dst + (size_t)d * SEQ + c4) = v;
  }
}

// Flash attention v17: 32x32x16 MFMA restructure (m214 shape) on the r15
// skeleton. One 32-q tile per wave (q = l&31 both halves); QK 8 mfma, PV 8,
// ones 4. V reads become 8x b128 (lane col = d, keys contiguous). P->A-frag
// via v_permlane32_swap (HK r272 pattern: operand pair = (quad j0 word,
// quad j1 word), both outputs used). One scalar m/asum chain per lane-q;
// max needs ONE shfl_xor(32). MFMA-ones keeps asum in acc layout.
__global__ __launch_bounds__(256, 2) void k_attn(
    const unsigned short* __restrict__ qkv, const float* __restrict__ mask,
    const unsigned short* __restrict__ vt, unsigned short* __restrict__ aout)
{
  const int bid = blockIdx.x;
  const int b = bid & 7;            // batch -> XCD (768 = 8*96, bijective)
  const int g2 = bid >> 3;          // 0..95
  const int h = g2 % NH;
  const int nt = g2 / NH;           // 0..15
  const int t = threadIdx.x;
  const int w = t >> 6, l = t & 63;
  const int ql = l & 31, hl = l >> 5;
  const int q0w = nt * 128 + w * 32;   // wave covers q0w..q0w+31

  __shared__ unsigned short lK[2][4096];
  __shared__ unsigned short lV[2][4096];

  const unsigned short* kb = qkv + (size_t)(b * SEQ) * QKVN + CDIM + h * HD;
  const unsigned short* vb = vt + (size_t)(b * NH + h) * HD * SEQ;
  const float* mrowq = mask + ((size_t)b * SEQ + q0w + ql) * SEQ + 4 * hl;

  // staging: 256 threads x 16B x 2 issues = 64x64 bf16 tile; source pre-swizzled
  const int trow = t >> 3, tg = t & 7;
  const int glog = tg ^ (trow & 7);
  const size_t kSrc = (size_t)trow * QKVN + glog * 8;
  const size_t vSrc = (size_t)trow * SEQ + glog * 8;
  const int tid8 = t * 8;

  // fragment b128 read offsets (elems). Chunk i (d-chunk for K, key-chunk for
  // V): rows ql (blk0) / 32+ql (blk1), granule (2i+hl)^(ql&7). (32+ql)&7==ql&7.
  const int qx = ql & 7;
  int off0[4], off1[4];
#pragma unroll
  for (int i = 0; i < 4; ++i) {
    const int g = ((2 * i + hl) ^ qx) * 8;
    off0[i] = ql * 64 + g;
    off1[i] = (32 + ql) * 64 + g;
  }

  // Q as B-frag: lane provides Q[q=ql][d = 16m+8hl .. +7]; prescaled by
  // rsqrt(D)*log2(e) -> log2-domain scores.
  const unsigned short* qb = qkv + (size_t)(b * SEQ + q0w + ql) * QKVN + h * HD;
  bf16x8 qf[4];
#pragma unroll
  for (int m = 0; m < 4; ++m) {
    qf[m] = *(const bf16x8*)(qb + 16 * m + 8 * hl);
#pragma unroll
    for (int i = 0; i < 8; ++i)
      qf[m][i] = (__bf16)((float)qf[m][i] * 0.18033688f);
  }

  const __bf16 one = (__bf16)1.0f;
  const bf16x8 vones = {one, one, one, one, one, one, one, one};
  f32x16 acco0, acco1, asum;
#pragma unroll
  for (int i = 0; i < 16; ++i) { acco0[i] = 0.f; acco1[i] = 0.f; asum[i] = 0.f; }
  float mreg = -INFINITY;

  // prologue: stage kt=0 into buf 0
#pragma unroll
  for (int j = 0; j < 2; ++j) {
    gload_lds16(kb + (size_t)j * 32 * QKVN + kSrc, &lK[0][j * 2048 + tid8]);
    gload_lds16(vb + (size_t)j * 32 * SEQ + vSrc, &lV[0][j * 2048 + tid8]);
  }
  int buf = 0;

  for (int kt = 0; kt < SEQ; kt += 64) {
    const bool haveNext = (kt + 64 < SEQ);
    __syncthreads();
    if (haveNext) {
#pragma unroll
      for (int j = 0; j < 2; ++j) {
        gload_lds16(kb + (size_t)(kt + 64 + j * 32) * QKVN + kSrc, &lK[buf ^ 1][j * 2048 + tid8]);
        gload_lds16(vb + (kt + 64) + (size_t)j * 32 * SEQ + vSrc, &lV[buf ^ 1][j * 2048 + tid8]);
      }
    }

    // mask: lane q=ql, keys kt + 8s + 4hl + {0..3}, s=0..7
    float4 mk[8];
#pragma unroll
    for (int s = 0; s < 8; ++s)
      mk[s] = *(const float4*)(mrowq + kt + 8 * s);

    // swapped QK^T (32x32x16): S^T[key][q=ql]; key-blocks 0/1 (32 keys each)
    f32x16 s0, s1;
#pragma unroll
    for (int i = 0; i < 16; ++i) { s0[i] = 0.f; s1[i] = 0.f; }
    __builtin_amdgcn_s_setprio(1);
#pragma unroll
    for (int m = 0; m < 4; ++m) {
      bf16x8 kfa = *(const bf16x8*)&lK[buf][off0[m]];
      bf16x8 kfb = *(const bf16x8*)&lK[buf][off1[m]];
      s0 = __builtin_amdgcn_mfma_f32_32x32x16_bf16(kfa, qf[m], s0, 0, 0, 0);
      s1 = __builtin_amdgcn_mfma_f32_32x32x16_bf16(kfb, qf[m], s1, 0, 0, 0);
    }
    __builtin_amdgcn_s_setprio(0);

    // masked log2-scores: reg=4j+r holds key blk*32 + 8j + 4hl + r -> mk[blk*4+j][r]
#pragma unroll
    for (int j = 0; j < 4; ++j) {
      const float* m0 = (const float*)&mk[j];
      const float* m1 = (const float*)&mk[4 + j];
#pragma unroll
      for (int r = 0; r < 4; ++r) {
        s0[4 * j + r] = fmaf(m0[r], -144269.50f, s0[4 * j + r]);
        s1[4 * j + r] = fmaf(m1[r], -144269.50f, s1[4 * j + r]);
      }
    }

    // per-lane max over own 32 keys (partner half has the other 32): 1 shfl
    float tm = fmaxf(fmaxf(s0[0], s0[1]), fmaxf(s0[2], s0[3]));
#pragma unroll
    for (int i = 4; i < 16; i += 4)
      tm = fmaxf(tm, fmaxf(fmaxf(s0[i], s0[i + 1]), fmaxf(s0[i + 2], s0[i + 3])));
#pragma unroll
    for (int i = 0; i < 16; i += 4)
      tm = fmaxf(tm, fmaxf(fmaxf(s1[i], s1[i + 1]), fmaxf(s1[i + 2], s1[i + 3])));
    tm = fmaxf(tm, __shfl_xor(tm, 32));

    // defer-rescale (T13, thr=8 log2). al lives at lane q; broadcast to the
    // 16 acc rows via bpermute only when triggered (~5/32 iters).
    if (__any(tm > mreg + 8.f)) {
      const float mn = fmaxf(mreg, tm);
      const float al = __builtin_amdgcn_exp2f(mreg - mn);
      mreg = mn;
#pragma unroll
      for (int reg = 0; reg < 16; ++reg) {
        const float alr = __shfl(al, (reg & 3) + 8 * (reg >> 2) + 4 * hl);
        asum[reg] *= alr;
        acco0[reg] *= alr;
        acco1[reg] *= alr;
      }
    }

    // P = exp2(s - m)
#pragma unroll
    for (int i = 0; i < 16; ++i) {
      s0[i] = __builtin_amdgcn_exp2f(s0[i] - mreg);
      s1[i] = __builtin_amdgcn_exp2f(s1[i] - mreg);
    }

    // pack quads: pk[blk][2j+i] = bf16x2 of keys blk*32+8j+4hl+2i+{0,1}
    unsigned pk0[8], pk1[8];
#pragma unroll
    for (int j = 0; j < 4; ++j) {
      asm("v_cvt_pk_bf16_f32 %0, %1, %2" : "=v"(pk0[2 * j]) : "v"(s0[4 * j]), "v"(s0[4 * j + 1]));
      asm("v_cvt_pk_bf16_f32 %0, %1, %2" : "=v"(pk0[2 * j + 1]) : "v"(s0[4 * j + 2]), "v"(s0[4 * j + 3]));
      asm("v_cvt_pk_bf16_f32 %0, %1, %2" : "=v"(pk1[2 * j]) : "v"(s1[4 * j]), "v"(s1[4 * j + 1]));
      asm("v_cvt_pk_bf16_f32 %0, %1, %2" : "=v"(pk1[2 * j + 1]) : "v"(s1[4 * j + 2]), "v"(s1[4 * j + 3]));
    }

    // PV + MFMA-ones rowsum. Chunk kc covers keys 16kc..+15; A-frag built
    // from own quad j0=2*(kc&1) and j1=j0+1 via permlane32_swap (both
    // outputs used: A = [x0, x1, y0, y1] uniformly across lane halves).
    __builtin_amdgcn_s_setprio(1);
#pragma unroll
    for (int kc = 0; kc < 4; ++kc) {
      const unsigned* pkb = (kc < 2) ? pk0 : pk1;
      const int base = 4 * (kc & 1);
      unsigned x0 = pkb[base + 0], y0 = pkb[base + 2];
      unsigned x1 = pkb[base + 1], y1 = pkb[base + 3];
      asm("v_permlane32_swap_b32 %0, %1" : "+v"(x0), "+v"(y0));
      asm("v_permlane32_swap_b32 %0, %1" : "+v"(x1), "+v"(y1));
      union { unsigned u[4]; bf16x8 v; } A;
      A.u[0] = x0; A.u[1] = x1; A.u[2] = y0; A.u[3] = y1;
      asum = __builtin_amdgcn_mfma_f32_32x32x16_bf16(A.v, vones, asum, 0, 0, 0);
      bf16x8 vf0 = *(const bf16x8*)&lV[buf][off0[kc]];   // d = ql (block 0)
      bf16x8 vf1 = *(const bf16x8*)&lV[buf][off1[kc]];   // d = 32+ql (block 1)
      acco0 = __builtin_amdgcn_mfma_f32_32x32x16_bf16(A.v, vf0, acco0, 0, 0, 0);
      acco1 = __builtin_amdgcn_mfma_f32_32x32x16_bf16(A.v, vf1, acco1, 0, 0, 0);
    }
    __builtin_amdgcn_s_setprio(0);
    buf ^= 1;
  }

  // epilogue: rows q = (reg&3)+8*(reg>>2)+4*hl; cols d = ql / 32+ql
  unsigned short* ob = aout + (size_t)(b * SEQ + q0w) * CDIM + h * HD;
#pragma unroll
  for (int reg = 0; reg < 16; ++reg) {
    const float inv = 1.0f / asum[reg];
    const int qrow = (reg & 3) + 8 * (reg >> 2) + 4 * hl;
    ob[(size_t)qrow * CDIM + ql] = f2bf(acco0[reg] * inv);
    ob[(size_t)qrow * CDIM + 32 + ql] = f2bf(acco1[reg] * inv);
  }
}

extern "C" void kernel_launch(void* const* d_in, const int* in_sizes, int n_in,
                              void* d_out, int out_size, void* d_ws, size_t ws_size,
                              hipStream_t stream) {
  (void)in_sizes; (void)n_in; (void)out_size; (void)ws_size;
  const float* x      = (const float*)d_in[0];
  const float* mask   = (const float*)d_in[2];
  const float* qkv_w  = (const float*)d_in[3];
  const float* proj_w = (const float*)d_in[4];
  const float* proj_b = (const float*)d_in[5];
  float* out = (float*)d_out;
  char* ws = (char*)d_ws;

  unsigned short* xb    = (unsigned short*)(ws + 0);         // x bf16:      12,582,912
  unsigned short* wqb   = (unsigned short*)(ws + 12582912);  // qkv_w bf16:     884,736
  unsigned short* wpb   = (unsigned short*)(ws + 13467648);  // proj_w bf16:    294,912
  unsigned short* qkvb  = (unsigned short*)(ws + 13762560);  // qkv bf16:    37,748,736
  unsigned short* vtb   = (unsigned short*)(ws + 51511296);  // V^T bf16:    12,582,912
  unsigned short* aoutb = (unsigned short*)(ws + 64094208);  // attn out:    12,582,912

  k_convert<<<6144, 256, 0, stream>>>(x, xb, 1572864);
  k_convert<<<432, 256, 0, stream>>>(qkv_w, wqb, 110592);
  k_convert<<<144, 256, 0, stream>>>(proj_w, wpb, 36864);
  k_gemm_bt<0><<<dim3(128, 9), 256, 0, stream>>>(xb, wqb, qkvb, nullptr, nullptr, 16384, 1152, 384);
  k_vtrans<<<dim3(48, 32), 256, 0, stream>>>(qkvb, vtb);
  k_attn<<<768, 256, 0, stream>>>(qkvb, mask, vtb, aoutb);
  k_gemm_bt<1><<<dim3(128, 3), 256, 0, stream>>>(aoutb, wpb, nullptr, out, proj_b, 16384, 384, 384);
}

// Round 18
// 177.723 us; speedup vs baseline: 1.4467x; 1.0031x over previous
//
#include <hip/hip_runtime.h>
#include <stdint.h>
#include <math.h>

#define BB 8
#define SEQ 2048
#define CDIM 384
#define NH 6
#define HD 64
#define QKVN 1152

typedef __attribute__((ext_vector_type(8))) __bf16 bf16x8;
typedef __attribute__((ext_vector_type(4))) __bf16 bf16x4;
typedef __attribute__((ext_vector_type(4))) float f32x4;
typedef __attribute__((ext_vector_type(4))) unsigned short ushort4v;

__device__ __forceinline__ unsigned short f2bf(float f) {
  unsigned int u = __float_as_uint(f);
  u += 0x7fffu + ((u >> 16) & 1u);
  return (unsigned short)(u >> 16);
}

// fp32 -> bf16 conversion, 4 elems/thread
__global__ void k_convert(const float* __restrict__ src, unsigned short* __restrict__ dst, int n4) {
  int i = blockIdx.x * blockDim.x + threadIdx.x;
  if (i >= n4) return;
  float4 f = reinterpret_cast<const float4*>(src)[i];
  ushort4v u;
  u.x = f2bf(f.x); u.y = f2bf(f.y); u.z = f2bf(f.z); u.w = f2bf(f.w);
  reinterpret_cast<ushort4v*>(dst)[i] = u;
}

__device__ __forceinline__ void gload_lds16(const unsigned short* g, unsigned short* l) {
  __builtin_amdgcn_global_load_lds((const __attribute__((address_space(1))) void*)g,
                                   (__attribute__((address_space(3))) void*)l, 16, 0, 0);
}

// C[M,Nc] = A[M,K] * Bm[Nc,K]^T   (both row-major bf16, K contiguous; m97 structure)
template<int OUT_F32>
__global__ __launch_bounds__(256, 2) void k_gemm_bt(
    const unsigned short* __restrict__ A, const unsigned short* __restrict__ Bm,
    unsigned short* __restrict__ Cb, float* __restrict__ Cf,
    const float* __restrict__ bias, int M, int Nc, int K)
{
  __shared__ unsigned short lA[128 * 32];
  __shared__ unsigned short lB[128 * 32];
  const int t = threadIdx.x;
  const int w = t >> 6, l = t & 63;
  const int wr = w >> 1, wc = w & 1;
  const int row0 = blockIdx.x * 128, col0 = blockIdx.y * 128;
  const f32x4 vzero = {0.f, 0.f, 0.f, 0.f};
  f32x4 acc[4][4];
#pragma unroll
  for (int m = 0; m < 4; ++m)
#pragma unroll
    for (int n = 0; n < 4; ++n) acc[m][n] = vzero;

  const int srow = w * 16 + (l >> 2);
  const int scol = (l & 3) * 8;
  const int lr = l & 15, kc = (l >> 4) * 8;

  for (int k0 = 0; k0 < K; k0 += 32) {
#pragma unroll
    for (int r = 0; r < 2; ++r) {
      gload_lds16(A + (size_t)(row0 + r * 64 + srow) * K + k0 + scol,
                  &lA[(r * 64 + srow) * 32 + scol]);
      gload_lds16(Bm + (size_t)(col0 + r * 64 + srow) * K + k0 + scol,
                  &lB[(r * 64 + srow) * 32 + scol]);
    }
    __syncthreads();
    bf16x8 af[4], bfr[4];
#pragma unroll
    for (int m = 0; m < 4; ++m)
      af[m] = *(const bf16x8*)&lA[(wr * 64 + m * 16 + lr) * 32 + kc];
#pragma unroll
    for (int n = 0; n < 4; ++n)
      bfr[n] = *(const bf16x8*)&lB[(wc * 64 + n * 16 + lr) * 32 + kc];
#pragma unroll
    for (int m = 0; m < 4; ++m)
#pragma unroll
      for (int n = 0; n < 4; ++n)
        acc[m][n] = __builtin_amdgcn_mfma_f32_16x16x32_bf16(af[m], bfr[n], acc[m][n], 0, 0, 0);
    __syncthreads();
  }

#pragma unroll
  for (int m = 0; m < 4; ++m) {
    const int row = row0 + wr * 64 + m * 16 + (l >> 4) * 4;
#pragma unroll
    for (int n = 0; n < 4; ++n) {
      const int col = col0 + wc * 64 + n * 16 + (l & 15);
      if (OUT_F32) {
        const float bv = bias[col];
#pragma unroll
        for (int j = 0; j < 4; ++j)
          Cf[(size_t)(row + j) * Nc + col] = acc[m][n][j] + bv;
      } else {
#pragma unroll
        for (int j = 0; j < 4; ++j)
          Cb[(size_t)(row + j) * Nc + col] = f2bf(acc[m][n][j]);
      }
    }
  }
}

// V slice of qkv (b,n,768 + h*64 + d) -> VT[(b*H+h), d, n]  (bf16)
__global__ void k_vtrans(const unsigned short* __restrict__ qkv, unsigned short* __restrict__ vt)
{
  __shared__ unsigned short tile[64][76];
  const int bh = blockIdx.x;
  const int b = bh / NH, h = bh - b * NH;
  const int n0 = blockIdx.y * 64;
  const int t = threadIdx.x;
  const int rr0 = t >> 4;
  const int c4 = (t & 15) * 4;
  const unsigned short* src = qkv + (size_t)(b * SEQ + n0) * QKVN + 2 * CDIM + h * HD;
#pragma unroll
  for (int rr = 0; rr < 4; ++rr) {
    int n = rr * 16 + rr0;
    ushort4v v = *(const ushort4v*)(src + (size_t)n * QKVN + c4);
    *(ushort4v*)&tile[n][c4] = v;
  }
  __syncthreads();
  unsigned short* dst = vt + (size_t)bh * HD * SEQ + n0;
#pragma unroll
  for (int rr = 0; rr < 4; ++rr) {
    int d = rr * 16 + rr0;
    ushort4v v;
    v.x = tile[c4 + 0][d];
    v.y = tile[c4 + 1][d];
    v.z = tile[c4 + 2][d];
    v.w = tile[c4 + 3][d];
    *(ushort4v*)(dst + (size_t)d * SEQ + c4) = v;
  }
}

// Flash attention v18 = r15 (best measured: 2 q-tiles/wave, dbuf K/V, direct
// P-pack, MFMA-ones rowsum, setprio, max3 trees) with the per-iteration VMEM
// issue ORDER fixed: masks (consumed mid-iter) issue BEFORE staging (consumed
// next iter). vmcnt is FIFO -- the old order (staging first) meant consuming
// the last mask required vmcnt(0), forcing the t+1 HBM staging to drain
// MID-ITERATION t. New order: mask consumption waits vmcnt(4), staging stays
// in flight until the next barrier. sched_barrier(0) pins the issue order.
__global__ __launch_bounds__(256, 3) void k_attn(
    const unsigned short* __restrict__ qkv, const float* __restrict__ mask,
    const unsigned short* __restrict__ vt, unsigned short* __restrict__ aout)
{
  const int bid = blockIdx.x;
  const int b = bid & 7;            // batch -> XCD (768 = 8*96, bijective)
  const int g2 = bid >> 3;          // 0..95
  const int h = g2 % NH;
  const int nt = g2 / NH;           // 0..15
  const int t = threadIdx.x;
  const int w = t >> 6, l = t & 63;
  const int gk = l >> 4, c = l & 15;
  const int q0 = nt * 128 + w * 16;   // tile0; tile1 = q0+64

  __shared__ unsigned short lK[2][4096];
  __shared__ unsigned short lV[2][4096];

  const unsigned short* qb0 = qkv + (size_t)(b * SEQ + q0) * QKVN + h * HD;
  const unsigned short* qb1 = qb0 + (size_t)64 * QKVN;
  const unsigned short* kb = qkv + (size_t)(b * SEQ) * QKVN + CDIM + h * HD;
  const unsigned short* vb = vt + (size_t)(b * NH + h) * HD * SEQ;
  const float* mrow0 = mask + ((size_t)b * SEQ + q0 + c) * SEQ + 4 * gk;
  const float* mrow1 = mrow0 + (size_t)64 * SEQ;

  // staging: 256 threads x 16B x 2 issues = 64x64 bf16 tile; source pre-swizzled
  const int trow = t >> 3, tg = t & 7;
  const int glog = tg ^ (trow & 7);
  const size_t kSrc = (size_t)trow * QKVN + glog * 8;
  const size_t vSrc = (size_t)trow * SEQ + glog * 8;
  const int tid8 = t * 8;

  // K fragment ds_read offsets (b128, elems)
  const int fr0 = c * 64 + ((gk) ^ (c & 7)) * 8;
  const int fr1 = c * 64 + ((4 + gk) ^ (c & 7)) * 8;
  // V b64 granule offsets (8B granule g at row c: phys = g ^ (2*(c&7)))
  const int cx2 = 2 * (c & 7);
  const int vg0 = c * 64 + ((gk) ^ cx2) * 4;       // keys 4gk..4gk+3
  const int vg1 = c * 64 + ((4 + gk) ^ cx2) * 4;   // keys 16+4gk..+3
  const int vg2 = c * 64 + ((8 + gk) ^ cx2) * 4;   // keys 32+4gk..+3
  const int vg3 = c * 64 + ((12 + gk) ^ cx2) * 4;  // keys 48+4gk..+3

  // Q as B'-frag (col=q=c, d-chunk gk*8), pre-scaled by rsqrt(D)*log2(e)
  bf16x8 qf00 = *(const bf16x8*)(qb0 + (size_t)c * QKVN + gk * 8);
  bf16x8 qf01 = *(const bf16x8*)(qb0 + (size_t)c * QKVN + 32 + gk * 8);
  bf16x8 qf10 = *(const bf16x8*)(qb1 + (size_t)c * QKVN + gk * 8);
  bf16x8 qf11 = *(const bf16x8*)(qb1 + (size_t)c * QKVN + 32 + gk * 8);
#pragma unroll
  for (int i = 0; i < 8; ++i) {
    qf00[i] = (__bf16)((float)qf00[i] * 0.18033688f);
    qf01[i] = (__bf16)((float)qf01[i] * 0.18033688f);
    qf10[i] = (__bf16)((float)qf10[i] * 0.18033688f);
    qf11[i] = (__bf16)((float)qf11[i] * 0.18033688f);
  }

  const __bf16 one = (__bf16)1.0f;
  const bf16x8 vones = {one, one, one, one, one, one, one, one};
  const f32x4 vzero = {0.f, 0.f, 0.f, 0.f};
  f32x4 acco0[4], acco1[4];
  f32x4 asum0 = vzero, asum1 = vzero;      // rowsum in ACC layout (q=4gk+r)
  float mreg0 = -INFINITY, mreg1 = -INFINITY;
#pragma unroll
  for (int dt = 0; dt < 4; ++dt) { acco0[dt] = vzero; acco1[dt] = vzero; }

  // prologue: stage kt=0 into buf 0
#pragma unroll
  for (int j = 0; j < 2; ++j) {
    gload_lds16(kb + (size_t)j * 32 * QKVN + kSrc, &lK[0][j * 2048 + tid8]);
    gload_lds16(vb + (size_t)j * 32 * SEQ + vSrc, &lV[0][j * 2048 + tid8]);
  }
  int buf = 0;

  for (int kt = 0; kt < SEQ; kt += 64) {
    const bool haveNext = (kt + 64 < SEQ);
    __syncthreads();

    // masks FIRST (consumed this iter -> drain waits only on these, vmcnt(4))
    float4 mk0[4], mk1[4];
#pragma unroll
    for (int j = 0; j < 4; ++j) {
      mk0[j] = *(const float4*)(mrow0 + kt + 16 * j);
      mk1[j] = *(const float4*)(mrow1 + kt + 16 * j);
    }
    __builtin_amdgcn_sched_barrier(0);   // pin: masks issue before staging

    // staging SECOND (consumed next iter; stays in flight to next barrier)
    if (haveNext) {
#pragma unroll
      for (int j = 0; j < 2; ++j) {
        gload_lds16(kb + (size_t)(kt + 64 + j * 32) * QKVN + kSrc, &lK[buf ^ 1][j * 2048 + tid8]);
        gload_lds16(vb + (kt + 64) + (size_t)j * 32 * SEQ + vSrc, &lV[buf ^ 1][j * 2048 + tid8]);
      }
    }

    // swapped QK^T for both tiles: each K-fragment read ONCE, used twice
    f32x4 s0[4], s1[4];
    __builtin_amdgcn_s_setprio(1);
#pragma unroll
    for (int j = 0; j < 4; ++j) {
      bf16x8 kfa = *(const bf16x8*)&lK[buf][j * 1024 + fr0];
      bf16x8 kfb = *(const bf16x8*)&lK[buf][j * 1024 + fr1];
      s0[j] = __builtin_amdgcn_mfma_f32_16x16x32_bf16(kfa, qf00, vzero, 0, 0, 0);
      s0[j] = __builtin_amdgcn_mfma_f32_16x16x32_bf16(kfb, qf01, s0[j], 0, 0, 0);
      s1[j] = __builtin_amdgcn_mfma_f32_16x16x32_bf16(kfa, qf10, vzero, 0, 0, 0);
      s1[j] = __builtin_amdgcn_mfma_f32_16x16x32_bf16(kfb, qf11, s1[j], 0, 0, 0);
    }
    __builtin_amdgcn_s_setprio(0);

    // masked log2-scores in place (two independent chains from here)
#pragma unroll
    for (int j = 0; j < 4; ++j) {
      const float* m0 = (const float*)&mk0[j];
      const float* m1 = (const float*)&mk1[j];
#pragma unroll
      for (int r = 0; r < 4; ++r) {
        s0[j][r] = fmaf(m0[r], -144269.50f, s0[j][r]);
        s1[j][r] = fmaf(m1[r], -144269.50f, s1[j][r]);
      }
    }

    // per-lane max (max3-shaped: 3-ary fmaxf nests fuse to v_max3_f32)
    float a0 = fmaxf(fmaxf(s0[0][0], s0[0][1]), s0[0][2]);
    float b0 = fmaxf(fmaxf(s0[0][3], s0[1][0]), s0[1][1]);
    float d0 = fmaxf(fmaxf(s0[1][2], s0[1][3]), s0[2][0]);
    float e0 = fmaxf(fmaxf(s0[2][1], s0[2][2]), s0[2][3]);
    float f0 = fmaxf(fmaxf(s0[3][0], s0[3][1]), s0[3][2]);
    float tm0 = fmaxf(fmaxf(fmaxf(a0, b0), d0), fmaxf(fmaxf(e0, f0), s0[3][3]));
    float a1 = fmaxf(fmaxf(s1[0][0], s1[0][1]), s1[0][2]);
    float b1 = fmaxf(fmaxf(s1[0][3], s1[1][0]), s1[1][1]);
    float d1 = fmaxf(fmaxf(s1[1][2], s1[1][3]), s1[2][0]);
    float e1 = fmaxf(fmaxf(s1[2][1], s1[2][2]), s1[2][3]);
    float f1 = fmaxf(fmaxf(s1[3][0], s1[3][1]), s1[3][2]);
    float tm1 = fmaxf(fmaxf(fmaxf(a1, b1), d1), fmaxf(fmaxf(e1, f1), s1[3][3]));
    tm0 = fmaxf(tm0, __shfl_xor(tm0, 16));
    tm1 = fmaxf(tm1, __shfl_xor(tm1, 16));
    tm0 = fmaxf(tm0, __shfl_xor(tm0, 32));
    tm1 = fmaxf(tm1, __shfl_xor(tm1, 32));

    // defer-rescale (T13, thr=8 in log2 domain), per tile
    if (__any(tm0 > mreg0 + 8.f)) {
      const float mn = fmaxf(mreg0, tm0);
      const float al = __builtin_amdgcn_exp2f(mreg0 - mn);
      mreg0 = mn;
      float alr[4];
#pragma unroll
      for (int r = 0; r < 4; ++r) alr[r] = __shfl(al, 20 * gk + r);
#pragma unroll
      for (int r = 0; r < 4; ++r) asum0[r] *= alr[r];
#pragma unroll
      for (int dt = 0; dt < 4; ++dt)
#pragma unroll
        for (int r = 0; r < 4; ++r) acco0[dt][r] *= alr[r];
    }
    if (__any(tm1 > mreg1 + 8.f)) {
      const float mn = fmaxf(mreg1, tm1);
      const float al = __builtin_amdgcn_exp2f(mreg1 - mn);
      mreg1 = mn;
      float alr[4];
#pragma unroll
      for (int r = 0; r < 4; ++r) alr[r] = __shfl(al, 20 * gk + r);
#pragma unroll
      for (int r = 0; r < 4; ++r) asum1[r] *= alr[r];
#pragma unroll
      for (int dt = 0; dt < 4; ++dt)
#pragma unroll
        for (int r = 0; r < 4; ++r) acco1[dt][r] *= alr[r];
    }

    // P = exp2(s - m) in place (rowsum handled by MFMA-ones below)
#pragma unroll
    for (int j = 0; j < 4; ++j)
#pragma unroll
      for (int r = 0; r < 4; ++r) {
        s0[j][r] = __builtin_amdgcn_exp2f(s0[j][r] - mreg0);
        s1[j][r] = __builtin_amdgcn_exp2f(s1[j][r] - mreg1);
      }

    // pack P -> A-fragments directly (k-slot permutation; no LDS round-trip)
    union { unsigned int u[8]; bf16x8 v[2]; } pu0, pu1;
#pragma unroll
    for (int j = 0; j < 4; ++j) {
      asm("v_cvt_pk_bf16_f32 %0, %1, %2" : "=v"(pu0.u[2 * j]) : "v"(s0[j][0]), "v"(s0[j][1]));
      asm("v_cvt_pk_bf16_f32 %0, %1, %2" : "=v"(pu0.u[2 * j + 1]) : "v"(s0[j][2]), "v"(s0[j][3]));
      asm("v_cvt_pk_bf16_f32 %0, %1, %2" : "=v"(pu1.u[2 * j]) : "v"(s1[j][0]), "v"(s1[j][1]));
      asm("v_cvt_pk_bf16_f32 %0, %1, %2" : "=v"(pu1.u[2 * j + 1]) : "v"(s1[j][2]), "v"(s1[j][3]));
    }

    // PV + MFMA-ones rowsum (asum emerges in acc layout q=4gk+r, all lanes)
    __builtin_amdgcn_s_setprio(1);
    asum0 = __builtin_amdgcn_mfma_f32_16x16x32_bf16(pu0.v[0], vones, asum0, 0, 0, 0);
    asum0 = __builtin_amdgcn_mfma_f32_16x16x32_bf16(pu0.v[1], vones, asum0, 0, 0, 0);
    asum1 = __builtin_amdgcn_mfma_f32_16x16x32_bf16(pu1.v[0], vones, asum1, 0, 0, 0);
    asum1 = __builtin_amdgcn_mfma_f32_16x16x32_bf16(pu1.v[1], vones, asum1, 0, 0, 0);
#pragma unroll
    for (int dt = 0; dt < 4; ++dt) {
      const unsigned short* vrow = &lV[buf][dt * 1024];
      bf16x4 a0v = *(const bf16x4*)(vrow + vg0);
      bf16x4 a1v = *(const bf16x4*)(vrow + vg1);
      bf16x4 a2v = *(const bf16x4*)(vrow + vg2);
      bf16x4 a3v = *(const bf16x4*)(vrow + vg3);
      bf16x8 vf0 = __builtin_shufflevector(a0v, a1v, 0, 1, 2, 3, 4, 5, 6, 7);
      bf16x8 vf1 = __builtin_shufflevector(a2v, a3v, 0, 1, 2, 3, 4, 5, 6, 7);
      acco0[dt] = __builtin_amdgcn_mfma_f32_16x16x32_bf16(pu0.v[0], vf0, acco0[dt], 0, 0, 0);
      acco0[dt] = __builtin_amdgcn_mfma_f32_16x16x32_bf16(pu0.v[1], vf1, acco0[dt], 0, 0, 0);
      acco1[dt] = __builtin_amdgcn_mfma_f32_16x16x32_bf16(pu1.v[0], vf0, acco1[dt], 0, 0, 0);
      acco1[dt] = __builtin_amdgcn_mfma_f32_16x16x32_bf16(pu1.v[1], vf1, acco1[dt], 0, 0, 0);
    }
    __builtin_amdgcn_s_setprio(0);
    buf ^= 1;
  }

  // normalize + store both tiles (asum already in acc layout: no shfl)
  float inv0[4], inv1[4];
#pragma unroll
  for (int r = 0; r < 4; ++r) {
    inv0[r] = 1.0f / asum0[r];
    inv1[r] = 1.0f / asum1[r];
  }
  unsigned short* ob0 = aout + (size_t)(b * SEQ + q0) * CDIM + h * HD;
  unsigned short* ob1 = ob0 + (size_t)64 * CDIM;
#pragma unroll
  for (int r = 0; r < 4; ++r)
#pragma unroll
    for (int dt = 0; dt < 4; ++dt) {
      ob0[(size_t)(4 * gk + r) * CDIM + dt * 16 + c] = f2bf(acco0[dt][r] * inv0[r]);
      ob1[(size_t)(4 * gk + r) * CDIM + dt * 16 + c] = f2bf(acco1[dt][r] * inv1[r]);
    }
}

extern "C" void kernel_launch(void* const* d_in, const int* in_sizes, int n_in,
                              void* d_out, int out_size, void* d_ws, size_t ws_size,
                              hipStream_t stream) {
  (void)in_sizes; (void)n_in; (void)out_size; (void)ws_size;
  const float* x      = (const float*)d_in[0];
  const float* mask   = (const float*)d_in[2];
  const float* qkv_w  = (const float*)d_in[3];
  const float* proj_w = (const float*)d_in[4];
  const float* proj_b = (const float*)d_in[5];
  float* out = (float*)d_out;
  char* ws = (char*)d_ws;

  unsigned short* xb    = (unsigned short*)(ws + 0);         // x bf16:      12,582,912
  unsigned short* wqb   = (unsigned short*)(ws + 12582912);  // qkv_w bf16:     884,736
  unsigned short* wpb   = (unsigned short*)(ws + 13467648);  // proj_w bf16:    294,912
  unsigned short* qkvb  = (unsigned short*)(ws + 13762560);  // qkv bf16:    37,748,736
  unsigned short* vtb   = (unsigned short*)(ws + 51511296);  // V^T bf16:    12,582,912
  unsigned short* aoutb = (unsigned short*)(ws + 64094208);  // attn out:    12,582,912

  k_convert<<<6144, 256, 0, stream>>>(x, xb, 1572864);
  k_convert<<<432, 256, 0, stream>>>(qkv_w, wqb, 110592);
  k_convert<<<144, 256, 0, stream>>>(proj_w, wpb, 36864);
  k_gemm_bt<0><<<dim3(128, 9), 256, 0, stream>>>(xb, wqb, qkvb, nullptr, nullptr, 16384, 1152, 384);
  k_vtrans<<<dim3(48, 32), 256, 0, stream>>>(qkvb, vtb);
  k_attn<<<768, 256, 0, stream>>>(qkvb, mask, vtb, aoutb);
  k_gemm_bt<1><<<dim3(128, 3), 256, 0, stream>>>(aoutb, wpb, nullptr, out, proj_b, 16384, 384, 384);
}

// Round 19
// 169.610 us; speedup vs baseline: 1.5159x; 1.0478x over previous
//
#include <hip/hip_runtime.h>
#include <stdint.h>
#include <math.h>

#define BB 8
#define SEQ 2048
#define CDIM 384
#define NH 6
#define HD 64
#define QKVN 1152

typedef __attribute__((ext_vector_type(8))) __bf16 bf16x8;
typedef __attribute__((ext_vector_type(4))) __bf16 bf16x4;
typedef __attribute__((ext_vector_type(4))) float f32x4;
typedef __attribute__((ext_vector_type(4))) unsigned short ushort4v;

__device__ __forceinline__ unsigned short f2bf(float f) {
  unsigned int u = __float_as_uint(f);
  u += 0x7fffu + ((u >> 16) & 1u);
  return (unsigned short)(u >> 16);
}

// merged fp32 -> bf16 conversion over three tensors (x, qkv_w, proj_w):
// one launch instead of three (saves 2 graph-dispatch overheads).
#define N4_X  1572864
#define N4_WQ 110592
#define N4_WP 36864
__global__ void k_convert3(const float* __restrict__ x, unsigned short* __restrict__ xb,
                           const float* __restrict__ wq, unsigned short* __restrict__ wqb,
                           const float* __restrict__ wp, unsigned short* __restrict__ wpb) {
  int i = blockIdx.x * blockDim.x + threadIdx.x;
  const float* src;
  unsigned short* dst;
  int j;
  if (i < N4_X) { src = x; dst = xb; j = i; }
  else if (i < N4_X + N4_WQ) { src = wq; dst = wqb; j = i - N4_X; }
  else if (i < N4_X + N4_WQ + N4_WP) { src = wp; dst = wpb; j = i - N4_X - N4_WQ; }
  else return;
  float4 f = reinterpret_cast<const float4*>(src)[j];
  ushort4v u;
  u.x = f2bf(f.x); u.y = f2bf(f.y); u.z = f2bf(f.z); u.w = f2bf(f.w);
  reinterpret_cast<ushort4v*>(dst)[j] = u;
}

__device__ __forceinline__ void gload_lds16(const unsigned short* g, unsigned short* l) {
  __builtin_amdgcn_global_load_lds((const __attribute__((address_space(1))) void*)g,
                                   (__attribute__((address_space(3))) void*)l, 16, 0, 0);
}

// C[M,Nc] = A[M,K] * Bm[Nc,K]^T   (both row-major bf16, K contiguous; m97 structure)
template<int OUT_F32>
__global__ __launch_bounds__(256, 2) void k_gemm_bt(
    const unsigned short* __restrict__ A, const unsigned short* __restrict__ Bm,
    unsigned short* __restrict__ Cb, float* __restrict__ Cf,
    const float* __restrict__ bias, int M, int Nc, int K)
{
  __shared__ unsigned short lA[128 * 32];
  __shared__ unsigned short lB[128 * 32];
  const int t = threadIdx.x;
  const int w = t >> 6, l = t & 63;
  const int wr = w >> 1, wc = w & 1;
  const int row0 = blockIdx.x * 128, col0 = blockIdx.y * 128;
  const f32x4 vzero = {0.f, 0.f, 0.f, 0.f};
  f32x4 acc[4][4];
#pragma unroll
  for (int m = 0; m < 4; ++m)
#pragma unroll
    for (int n = 0; n < 4; ++n) acc[m][n] = vzero;

  const int srow = w * 16 + (l >> 2);
  const int scol = (l & 3) * 8;
  const int lr = l & 15, kc = (l >> 4) * 8;

  for (int k0 = 0; k0 < K; k0 += 32) {
#pragma unroll
    for (int r = 0; r < 2; ++r) {
      gload_lds16(A + (size_t)(row0 + r * 64 + srow) * K + k0 + scol,
                  &lA[(r * 64 + srow) * 32 + scol]);
      gload_lds16(Bm + (size_t)(col0 + r * 64 + srow) * K + k0 + scol,
                  &lB[(r * 64 + srow) * 32 + scol]);
    }
    __syncthreads();
    bf16x8 af[4], bfr[4];
#pragma unroll
    for (int m = 0; m < 4; ++m)
      af[m] = *(const bf16x8*)&lA[(wr * 64 + m * 16 + lr) * 32 + kc];
#pragma unroll
    for (int n = 0; n < 4; ++n)
      bfr[n] = *(const bf16x8*)&lB[(wc * 64 + n * 16 + lr) * 32 + kc];
#pragma unroll
    for (int m = 0; m < 4; ++m)
#pragma unroll
      for (int n = 0; n < 4; ++n)
        acc[m][n] = __builtin_amdgcn_mfma_f32_16x16x32_bf16(af[m], bfr[n], acc[m][n], 0, 0, 0);
    __syncthreads();
  }

#pragma unroll
  for (int m = 0; m < 4; ++m) {
    const int row = row0 + wr * 64 + m * 16 + (l >> 4) * 4;
#pragma unroll
    for (int n = 0; n < 4; ++n) {
      const int col = col0 + wc * 64 + n * 16 + (l & 15);
      if (OUT_F32) {
        const float bv = bias[col];
#pragma unroll
        for (int j = 0; j < 4; ++j)
          Cf[(size_t)(row + j) * Nc + col] = acc[m][n][j] + bv;
      } else {
#pragma unroll
        for (int j = 0; j < 4; ++j)
          Cb[(size_t)(row + j) * Nc + col] = f2bf(acc[m][n][j]);
      }
    }
  }
}

// V slice of qkv (b,n,768 + h*64 + d) -> VT[(b*H+h), d, n]  (bf16)
__global__ void k_vtrans(const unsigned short* __restrict__ qkv, unsigned short* __restrict__ vt)
{
  __shared__ unsigned short tile[64][76];
  const int bh = blockIdx.x;
  const int b = bh / NH, h = bh - b * NH;
  const int n0 = blockIdx.y * 64;
  const int t = threadIdx.x;
  const int rr0 = t >> 4;
  const int c4 = (t & 15) * 4;
  const unsigned short* src = qkv + (size_t)(b * SEQ + n0) * QKVN + 2 * CDIM + h * HD;
#pragma unroll
  for (int rr = 0; rr < 4; ++rr) {
    int n = rr * 16 + rr0;
    ushort4v v = *(const ushort4v*)(src + (size_t)n * QKVN + c4);
    *(ushort4v*)&tile[n][c4] = v;
  }
  __syncthreads();
  unsigned short* dst = vt + (size_t)bh * HD * SEQ + n0;
#pragma unroll
  for (int rr = 0; rr < 4; ++rr) {
    int d = rr * 16 + rr0;
    ushort4v v;
    v.x = tile[c4 + 0][d];
    v.y = tile[c4 + 1][d];
    v.z = tile[c4 + 2][d];
    v.w = tile[c4 + 3][d];
    *(ushort4v*)(dst + (size_t)d * SEQ + c4) = v;
  }
}

// Flash attention v19 == r18 (best measured): 2 q-tiles/wave, dbuf K/V,
// direct P-pack, MFMA-ones rowsum, setprio, max3 trees, masks-before-staging.
__global__ __launch_bounds__(256, 3) void k_attn(
    const unsigned short* __restrict__ qkv, const float* __restrict__ mask,
    const unsigned short* __restrict__ vt, unsigned short* __restrict__ aout)
{
  const int bid = blockIdx.x;
  const int b = bid & 7;            // batch -> XCD (768 = 8*96, bijective)
  const int g2 = bid >> 3;          // 0..95
  const int h = g2 % NH;
  const int nt = g2 / NH;           // 0..15
  const int t = threadIdx.x;
  const int w = t >> 6, l = t & 63;
  const int gk = l >> 4, c = l & 15;
  const int q0 = nt * 128 + w * 16;   // tile0; tile1 = q0+64

  __shared__ unsigned short lK[2][4096];
  __shared__ unsigned short lV[2][4096];

  const unsigned short* qb0 = qkv + (size_t)(b * SEQ + q0) * QKVN + h * HD;
  const unsigned short* qb1 = qb0 + (size_t)64 * QKVN;
  const unsigned short* kb = qkv + (size_t)(b * SEQ) * QKVN + CDIM + h * HD;
  const unsigned short* vb = vt + (size_t)(b * NH + h) * HD * SEQ;
  const float* mrow0 = mask + ((size_t)b * SEQ + q0 + c) * SEQ + 4 * gk;
  const float* mrow1 = mrow0 + (size_t)64 * SEQ;

  // staging: 256 threads x 16B x 2 issues = 64x64 bf16 tile; source pre-swizzled
  const int trow = t >> 3, tg = t & 7;
  const int glog = tg ^ (trow & 7);
  const size_t kSrc = (size_t)trow * QKVN + glog * 8;
  const size_t vSrc = (size_t)trow * SEQ + glog * 8;
  const int tid8 = t * 8;

  // K fragment ds_read offsets (b128, elems)
  const int fr0 = c * 64 + ((gk) ^ (c & 7)) * 8;
  const int fr1 = c * 64 + ((4 + gk) ^ (c & 7)) * 8;
  // V b64 granule offsets (8B granule g at row c: phys = g ^ (2*(c&7)))
  const int cx2 = 2 * (c & 7);
  const int vg0 = c * 64 + ((gk) ^ cx2) * 4;       // keys 4gk..4gk+3
  const int vg1 = c * 64 + ((4 + gk) ^ cx2) * 4;   // keys 16+4gk..+3
  const int vg2 = c * 64 + ((8 + gk) ^ cx2) * 4;   // keys 32+4gk..+3
  const int vg3 = c * 64 + ((12 + gk) ^ cx2) * 4;  // keys 48+4gk..+3

  // Q as B'-frag (col=q=c, d-chunk gk*8), pre-scaled by rsqrt(D)*log2(e)
  bf16x8 qf00 = *(const bf16x8*)(qb0 + (size_t)c * QKVN + gk * 8);
  bf16x8 qf01 = *(const bf16x8*)(qb0 + (size_t)c * QKVN + 32 + gk * 8);
  bf16x8 qf10 = *(const bf16x8*)(qb1 + (size_t)c * QKVN + gk * 8);
  bf16x8 qf11 = *(const bf16x8*)(qb1 + (size_t)c * QKVN + 32 + gk * 8);
#pragma unroll
  for (int i = 0; i < 8; ++i) {
    qf00[i] = (__bf16)((float)qf00[i] * 0.18033688f);
    qf01[i] = (__bf16)((float)qf01[i] * 0.18033688f);
    qf10[i] = (__bf16)((float)qf10[i] * 0.18033688f);
    qf11[i] = (__bf16)((float)qf11[i] * 0.18033688f);
  }

  const __bf16 one = (__bf16)1.0f;
  const bf16x8 vones = {one, one, one, one, one, one, one, one};
  const f32x4 vzero = {0.f, 0.f, 0.f, 0.f};
  f32x4 acco0[4], acco1[4];
  f32x4 asum0 = vzero, asum1 = vzero;      // rowsum in ACC layout (q=4gk+r)
  float mreg0 = -INFINITY, mreg1 = -INFINITY;
#pragma unroll
  for (int dt = 0; dt < 4; ++dt) { acco0[dt] = vzero; acco1[dt] = vzero; }

  // prologue: stage kt=0 into buf 0
#pragma unroll
  for (int j = 0; j < 2; ++j) {
    gload_lds16(kb + (size_t)j * 32 * QKVN + kSrc, &lK[0][j * 2048 + tid8]);
    gload_lds16(vb + (size_t)j * 32 * SEQ + vSrc, &lV[0][j * 2048 + tid8]);
  }
  int buf = 0;

  for (int kt = 0; kt < SEQ; kt += 64) {
    const bool haveNext = (kt + 64 < SEQ);
    __syncthreads();

    // masks FIRST (consumed this iter), staging SECOND (consumed next iter)
    float4 mk0[4], mk1[4];
#pragma unroll
    for (int j = 0; j < 4; ++j) {
      mk0[j] = *(const float4*)(mrow0 + kt + 16 * j);
      mk1[j] = *(const float4*)(mrow1 + kt + 16 * j);
    }
    __builtin_amdgcn_sched_barrier(0);

    if (haveNext) {
#pragma unroll
      for (int j = 0; j < 2; ++j) {
        gload_lds16(kb + (size_t)(kt + 64 + j * 32) * QKVN + kSrc, &lK[buf ^ 1][j * 2048 + tid8]);
        gload_lds16(vb + (kt + 64) + (size_t)j * 32 * SEQ + vSrc, &lV[buf ^ 1][j * 2048 + tid8]);
      }
    }

    // swapped QK^T for both tiles: each K-fragment read ONCE, used twice
    f32x4 s0[4], s1[4];
    __builtin_amdgcn_s_setprio(1);
#pragma unroll
    for (int j = 0; j < 4; ++j) {
      bf16x8 kfa = *(const bf16x8*)&lK[buf][j * 1024 + fr0];
      bf16x8 kfb = *(const bf16x8*)&lK[buf][j * 1024 + fr1];
      s0[j] = __builtin_amdgcn_mfma_f32_16x16x32_bf16(kfa, qf00, vzero, 0, 0, 0);
      s0[j] = __builtin_amdgcn_mfma_f32_16x16x32_bf16(kfb, qf01, s0[j], 0, 0, 0);
      s1[j] = __builtin_amdgcn_mfma_f32_16x16x32_bf16(kfa, qf10, vzero, 0, 0, 0);
      s1[j] = __builtin_amdgcn_mfma_f32_16x16x32_bf16(kfb, qf11, s1[j], 0, 0, 0);
    }
    __builtin_amdgcn_s_setprio(0);

    // masked log2-scores in place (two independent chains from here)
#pragma unroll
    for (int j = 0; j < 4; ++j) {
      const float* m0 = (const float*)&mk0[j];
      const float* m1 = (const float*)&mk1[j];
#pragma unroll
      for (int r = 0; r < 4; ++r) {
        s0[j][r] = fmaf(m0[r], -144269.50f, s0[j][r]);
        s1[j][r] = fmaf(m1[r], -144269.50f, s1[j][r]);
      }
    }

    // per-lane max (max3-shaped: 3-ary fmaxf nests fuse to v_max3_f32)
    float a0 = fmaxf(fmaxf(s0[0][0], s0[0][1]), s0[0][2]);
    float b0 = fmaxf(fmaxf(s0[0][3], s0[1][0]), s0[1][1]);
    float d0 = fmaxf(fmaxf(s0[1][2], s0[1][3]), s0[2][0]);
    float e0 = fmaxf(fmaxf(s0[2][1], s0[2][2]), s0[2][3]);
    float f0 = fmaxf(fmaxf(s0[3][0], s0[3][1]), s0[3][2]);
    float tm0 = fmaxf(fmaxf(fmaxf(a0, b0), d0), fmaxf(fmaxf(e0, f0), s0[3][3]));
    float a1 = fmaxf(fmaxf(s1[0][0], s1[0][1]), s1[0][2]);
    float b1 = fmaxf(fmaxf(s1[0][3], s1[1][0]), s1[1][1]);
    float d1 = fmaxf(fmaxf(s1[1][2], s1[1][3]), s1[2][0]);
    float e1 = fmaxf(fmaxf(s1[2][1], s1[2][2]), s1[2][3]);
    float f1 = fmaxf(fmaxf(s1[3][0], s1[3][1]), s1[3][2]);
    float tm1 = fmaxf(fmaxf(fmaxf(a1, b1), d1), fmaxf(fmaxf(e1, f1), s1[3][3]));
    tm0 = fmaxf(tm0, __shfl_xor(tm0, 16));
    tm1 = fmaxf(tm1, __shfl_xor(tm1, 16));
    tm0 = fmaxf(tm0, __shfl_xor(tm0, 32));
    tm1 = fmaxf(tm1, __shfl_xor(tm1, 32));

    // defer-rescale (T13, thr=8 in log2 domain), per tile
    if (__any(tm0 > mreg0 + 8.f)) {
      const float mn = fmaxf(mreg0, tm0);
      const float al = __builtin_amdgcn_exp2f(mreg0 - mn);
      mreg0 = mn;
      float alr[4];
#pragma unroll
      for (int r = 0; r < 4; ++r) alr[r] = __shfl(al, 20 * gk + r);
#pragma unroll
      for (int r = 0; r < 4; ++r) asum0[r] *= alr[r];
#pragma unroll
      for (int dt = 0; dt < 4; ++dt)
#pragma unroll
        for (int r = 0; r < 4; ++r) acco0[dt][r] *= alr[r];
    }
    if (__any(tm1 > mreg1 + 8.f)) {
      const float mn = fmaxf(mreg1, tm1);
      const float al = __builtin_amdgcn_exp2f(mreg1 - mn);
      mreg1 = mn;
      float alr[4];
#pragma unroll
      for (int r = 0; r < 4; ++r) alr[r] = __shfl(al, 20 * gk + r);
#pragma unroll
      for (int r = 0; r < 4; ++r) asum1[r] *= alr[r];
#pragma unroll
      for (int dt = 0; dt < 4; ++dt)
#pragma unroll
        for (int r = 0; r < 4; ++r) acco1[dt][r] *= alr[r];
    }

    // P = exp2(s - m) in place (rowsum handled by MFMA-ones below)
#pragma unroll
    for (int j = 0; j < 4; ++j)
#pragma unroll
      for (int r = 0; r < 4; ++r) {
        s0[j][r] = __builtin_amdgcn_exp2f(s0[j][r] - mreg0);
        s1[j][r] = __builtin_amdgcn_exp2f(s1[j][r] - mreg1);
      }

    // pack P -> A-fragments directly (k-slot permutation; no LDS round-trip)
    union { unsigned int u[8]; bf16x8 v[2]; } pu0, pu1;
#pragma unroll
    for (int j = 0; j < 4; ++j) {
      asm("v_cvt_pk_bf16_f32 %0, %1, %2" : "=v"(pu0.u[2 * j]) : "v"(s0[j][0]), "v"(s0[j][1]));
      asm("v_cvt_pk_bf16_f32 %0, %1, %2" : "=v"(pu0.u[2 * j + 1]) : "v"(s0[j][2]), "v"(s0[j][3]));
      asm("v_cvt_pk_bf16_f32 %0, %1, %2" : "=v"(pu1.u[2 * j]) : "v"(s1[j][0]), "v"(s1[j][1]));
      asm("v_cvt_pk_bf16_f32 %0, %1, %2" : "=v"(pu1.u[2 * j + 1]) : "v"(s1[j][2]), "v"(s1[j][3]));
    }

    // PV + MFMA-ones rowsum (asum emerges in acc layout q=4gk+r, all lanes)
    __builtin_amdgcn_s_setprio(1);
    asum0 = __builtin_amdgcn_mfma_f32_16x16x32_bf16(pu0.v[0], vones, asum0, 0, 0, 0);
    asum0 = __builtin_amdgcn_mfma_f32_16x16x32_bf16(pu0.v[1], vones, asum0, 0, 0, 0);
    asum1 = __builtin_amdgcn_mfma_f32_16x16x32_bf16(pu1.v[0], vones, asum1, 0, 0, 0);
    asum1 = __builtin_amdgcn_mfma_f32_16x16x32_bf16(pu1.v[1], vones, asum1, 0, 0, 0);
#pragma unroll
    for (int dt = 0; dt < 4; ++dt) {
      const unsigned short* vrow = &lV[buf][dt * 1024];
      bf16x4 a0v = *(const bf16x4*)(vrow + vg0);
      bf16x4 a1v = *(const bf16x4*)(vrow + vg1);
      bf16x4 a2v = *(const bf16x4*)(vrow + vg2);
      bf16x4 a3v = *(const bf16x4*)(vrow + vg3);
      bf16x8 vf0 = __builtin_shufflevector(a0v, a1v, 0, 1, 2, 3, 4, 5, 6, 7);
      bf16x8 vf1 = __builtin_shufflevector(a2v, a3v, 0, 1, 2, 3, 4, 5, 6, 7);
      acco0[dt] = __builtin_amdgcn_mfma_f32_16x16x32_bf16(pu0.v[0], vf0, acco0[dt], 0, 0, 0);
      acco0[dt] = __builtin_amdgcn_mfma_f32_16x16x32_bf16(pu0.v[1], vf1, acco0[dt], 0, 0, 0);
      acco1[dt] = __builtin_amdgcn_mfma_f32_16x16x32_bf16(pu1.v[0], vf0, acco1[dt], 0, 0, 0);
      acco1[dt] = __builtin_amdgcn_mfma_f32_16x16x32_bf16(pu1.v[1], vf1, acco1[dt], 0, 0, 0);
    }
    __builtin_amdgcn_s_setprio(0);
    buf ^= 1;
  }

  // normalize + store both tiles (asum already in acc layout: no shfl)
  float inv0[4], inv1[4];
#pragma unroll
  for (int r = 0; r < 4; ++r) {
    inv0[r] = 1.0f / asum0[r];
    inv1[r] = 1.0f / asum1[r];
  }
  unsigned short* ob0 = aout + (size_t)(b * SEQ + q0) * CDIM + h * HD;
  unsigned short* ob1 = ob0 + (size_t)64 * CDIM;
#pragma unroll
  for (int r = 0; r < 4; ++r)
#pragma unroll
    for (int dt = 0; dt < 4; ++dt) {
      ob0[(size_t)(4 * gk + r) * CDIM + dt * 16 + c] = f2bf(acco0[dt][r] * inv0[r]);
      ob1[(size_t)(4 * gk + r) * CDIM + dt * 16 + c] = f2bf(acco1[dt][r] * inv1[r]);
    }
}

extern "C" void kernel_launch(void* const* d_in, const int* in_sizes, int n_in,
                              void* d_out, int out_size, void* d_ws, size_t ws_size,
                              hipStream_t stream) {
  (void)in_sizes; (void)n_in; (void)out_size; (void)ws_size;
  const float* x      = (const float*)d_in[0];
  const float* mask   = (const float*)d_in[2];
  const float* qkv_w  = (const float*)d_in[3];
  const float* proj_w = (const float*)d_in[4];
  const float* proj_b = (const float*)d_in[5];
  float* out = (float*)d_out;
  char* ws = (char*)d_ws;

  unsigned short* xb    = (unsigned short*)(ws + 0);         // x bf16:      12,582,912
  unsigned short* wqb   = (unsigned short*)(ws + 12582912);  // qkv_w bf16:     884,736
  unsigned short* wpb   = (unsigned short*)(ws + 13467648);  // proj_w bf16:    294,912
  unsigned short* qkvb  = (unsigned short*)(ws + 13762560);  // qkv bf16:    37,748,736
  unsigned short* vtb   = (unsigned short*)(ws + 51511296);  // V^T bf16:    12,582,912
  unsigned short* aoutb = (unsigned short*)(ws + 64094208);  // attn out:    12,582,912

  // merged convert: (1572864 + 110592 + 36864) float4s = 1720320 -> 6720 blocks
  k_convert3<<<6720, 256, 0, stream>>>(x, xb, qkv_w, wqb, proj_w, wpb);
  k_gemm_bt<0><<<dim3(128, 9), 256, 0, stream>>>(xb, wqb, qkvb, nullptr, nullptr, 16384, 1152, 384);
  k_vtrans<<<dim3(48, 32), 256, 0, stream>>>(qkvb, vtb);
  k_attn<<<768, 256, 0, stream>>>(qkvb, mask, vtb, aoutb);
  k_gemm_bt<1><<<dim3(128, 3), 256, 0, stream>>>(aoutb, wpb, nullptr, out, proj_b, 16384, 384, 384);
}

// Round 20
// 165.895 us; speedup vs baseline: 1.5499x; 1.0224x over previous
//
#include <hip/hip_runtime.h>
#include <stdint.h>
#include <math.h>

#define BB 8
#define SEQ 2048
#define CDIM 384
#define NH 6
#define HD 64
#define QKVN 1152

typedef __attribute__((ext_vector_type(8))) __bf16 bf16x8;
typedef __attribute__((ext_vector_type(4))) __bf16 bf16x4;
typedef __attribute__((ext_vector_type(4))) float f32x4;
typedef __attribute__((ext_vector_type(4))) unsigned short ushort4v;

__device__ __forceinline__ unsigned short f2bf(float f) {
  unsigned int u = __float_as_uint(f);
  u += 0x7fffu + ((u >> 16) & 1u);
  return (unsigned short)(u >> 16);
}

// merged fp32 -> bf16 conversion over three tensors (x, qkv_w, proj_w)
#define N4_X  1572864
#define N4_WQ 110592
#define N4_WP 36864
__global__ void k_convert3(const float* __restrict__ x, unsigned short* __restrict__ xb,
                           const float* __restrict__ wq, unsigned short* __restrict__ wqb,
                           const float* __restrict__ wp, unsigned short* __restrict__ wpb) {
  int i = blockIdx.x * blockDim.x + threadIdx.x;
  const float* src;
  unsigned short* dst;
  int j;
  if (i < N4_X) { src = x; dst = xb; j = i; }
  else if (i < N4_X + N4_WQ) { src = wq; dst = wqb; j = i - N4_X; }
  else if (i < N4_X + N4_WQ + N4_WP) { src = wp; dst = wpb; j = i - N4_X - N4_WQ; }
  else return;
  float4 f = reinterpret_cast<const float4*>(src)[j];
  ushort4v u;
  u.x = f2bf(f.x); u.y = f2bf(f.y); u.z = f2bf(f.z); u.w = f2bf(f.w);
  reinterpret_cast<ushort4v*>(dst)[j] = u;
}

__device__ __forceinline__ void gload_lds16(const unsigned short* g, unsigned short* l) {
  __builtin_amdgcn_global_load_lds((const __attribute__((address_space(1))) void*)g,
                                   (__attribute__((address_space(3))) void*)l, 16, 0, 0);
}

// C[M,Nc] = A[M,K] * Bm[Nc,K]^T  (m97 structure).
// MODE 0 (QKV): Q/K column-tiles (col < 768) -> bf16 Cb; V column-tiles
//   (col >= 768, block-uniform since tiles are 128-wide) -> TRANSPOSED
//   directly into VT[(b*NH+h), d, n]  (folds the old k_vtrans kernel).
// MODE 1 (proj): f32 out with bias.
template<int MODE>
__global__ __launch_bounds__(256, 2) void k_gemm_bt(
    const unsigned short* __restrict__ A, const unsigned short* __restrict__ Bm,
    unsigned short* __restrict__ Cb, float* __restrict__ Cf,
    unsigned short* __restrict__ Vt,
    const float* __restrict__ bias, int M, int Nc, int K)
{
  __shared__ unsigned short lA[128 * 32];
  __shared__ unsigned short lB[128 * 32];
  const int t = threadIdx.x;
  const int w = t >> 6, l = t & 63;
  const int wr = w >> 1, wc = w & 1;
  const int row0 = blockIdx.x * 128, col0 = blockIdx.y * 128;
  const f32x4 vzero = {0.f, 0.f, 0.f, 0.f};
  f32x4 acc[4][4];
#pragma unroll
  for (int m = 0; m < 4; ++m)
#pragma unroll
    for (int n = 0; n < 4; ++n) acc[m][n] = vzero;

  const int srow = w * 16 + (l >> 2);
  const int scol = (l & 3) * 8;
  const int lr = l & 15, kc = (l >> 4) * 8;

  for (int k0 = 0; k0 < K; k0 += 32) {
#pragma unroll
    for (int r = 0; r < 2; ++r) {
      gload_lds16(A + (size_t)(row0 + r * 64 + srow) * K + k0 + scol,
                  &lA[(r * 64 + srow) * 32 + scol]);
      gload_lds16(Bm + (size_t)(col0 + r * 64 + srow) * K + k0 + scol,
                  &lB[(r * 64 + srow) * 32 + scol]);
    }
    __syncthreads();
    bf16x8 af[4], bfr[4];
#pragma unroll
    for (int m = 0; m < 4; ++m)
      af[m] = *(const bf16x8*)&lA[(wr * 64 + m * 16 + lr) * 32 + kc];
#pragma unroll
    for (int n = 0; n < 4; ++n)
      bfr[n] = *(const bf16x8*)&lB[(wc * 64 + n * 16 + lr) * 32 + kc];
#pragma unroll
    for (int m = 0; m < 4; ++m)
#pragma unroll
      for (int n = 0; n < 4; ++n)
        acc[m][n] = __builtin_amdgcn_mfma_f32_16x16x32_bf16(af[m], bfr[n], acc[m][n], 0, 0, 0);
    __syncthreads();
  }

  const bool vtile = (MODE == 0) && (col0 >= 2 * CDIM);
#pragma unroll
  for (int m = 0; m < 4; ++m) {
    const int row = row0 + wr * 64 + m * 16 + (l >> 4) * 4;
#pragma unroll
    for (int n = 0; n < 4; ++n) {
      const int col = col0 + wc * 64 + n * 16 + (l & 15);
      if (MODE == 1) {
        const float bv = bias[col];
#pragma unroll
        for (int j = 0; j < 4; ++j)
          Cf[(size_t)(row + j) * Nc + col] = acc[m][n][j] + bv;
      } else if (vtile) {
        // V tile: write transposed. d_global = col-768; b = row/SEQ (tile-
        // uniform since 128 | SEQ); token = row%SEQ. VT[(b*NH+h)*HD+d][token].
        const int dg = col - 2 * CDIM;
        const int bq = row >> 11;            // row/2048
        const int nn = row & 2047;
        unsigned short* vp = Vt + ((size_t)(bq * NH + (dg >> 6)) * HD + (dg & 63)) * SEQ + nn;
#pragma unroll
        for (int j = 0; j < 4; ++j)
          vp[j] = f2bf(acc[m][n][j]);
      } else {
#pragma unroll
        for (int j = 0; j < 4; ++j)
          Cb[(size_t)(row + j) * Nc + col] = f2bf(acc[m][n][j]);
      }
    }
  }
}

// Flash attention v20 == r18 (best measured): 2 q-tiles/wave, dbuf K/V,
// direct P-pack, MFMA-ones rowsum, setprio, max3 trees, masks-before-staging.
__global__ __launch_bounds__(256, 3) void k_attn(
    const unsigned short* __restrict__ qkv, const float* __restrict__ mask,
    const unsigned short* __restrict__ vt, unsigned short* __restrict__ aout)
{
  const int bid = blockIdx.x;
  const int b = bid & 7;            // batch -> XCD (768 = 8*96, bijective)
  const int g2 = bid >> 3;          // 0..95
  const int h = g2 % NH;
  const int nt = g2 / NH;           // 0..15
  const int t = threadIdx.x;
  const int w = t >> 6, l = t & 63;
  const int gk = l >> 4, c = l & 15;
  const int q0 = nt * 128 + w * 16;   // tile0; tile1 = q0+64

  __shared__ unsigned short lK[2][4096];
  __shared__ unsigned short lV[2][4096];

  const unsigned short* qb0 = qkv + (size_t)(b * SEQ + q0) * QKVN + h * HD;
  const unsigned short* qb1 = qb0 + (size_t)64 * QKVN;
  const unsigned short* kb = qkv + (size_t)(b * SEQ) * QKVN + CDIM + h * HD;
  const unsigned short* vb = vt + (size_t)(b * NH + h) * HD * SEQ;
  const float* mrow0 = mask + ((size_t)b * SEQ + q0 + c) * SEQ + 4 * gk;
  const float* mrow1 = mrow0 + (size_t)64 * SEQ;

  // staging: 256 threads x 16B x 2 issues = 64x64 bf16 tile; source pre-swizzled
  const int trow = t >> 3, tg = t & 7;
  const int glog = tg ^ (trow & 7);
  const size_t kSrc = (size_t)trow * QKVN + glog * 8;
  const size_t vSrc = (size_t)trow * SEQ + glog * 8;
  const int tid8 = t * 8;

  // K fragment ds_read offsets (b128, elems)
  const int fr0 = c * 64 + ((gk) ^ (c & 7)) * 8;
  const int fr1 = c * 64 + ((4 + gk) ^ (c & 7)) * 8;
  // V b64 granule offsets (8B granule g at row c: phys = g ^ (2*(c&7)))
  const int cx2 = 2 * (c & 7);
  const int vg0 = c * 64 + ((gk) ^ cx2) * 4;       // keys 4gk..4gk+3
  const int vg1 = c * 64 + ((4 + gk) ^ cx2) * 4;   // keys 16+4gk..+3
  const int vg2 = c * 64 + ((8 + gk) ^ cx2) * 4;   // keys 32+4gk..+3
  const int vg3 = c * 64 + ((12 + gk) ^ cx2) * 4;  // keys 48+4gk..+3

  // Q as B'-frag (col=q=c, d-chunk gk*8), pre-scaled by rsqrt(D)*log2(e)
  bf16x8 qf00 = *(const bf16x8*)(qb0 + (size_t)c * QKVN + gk * 8);
  bf16x8 qf01 = *(const bf16x8*)(qb0 + (size_t)c * QKVN + 32 + gk * 8);
  bf16x8 qf10 = *(const bf16x8*)(qb1 + (size_t)c * QKVN + gk * 8);
  bf16x8 qf11 = *(const bf16x8*)(qb1 + (size_t)c * QKVN + 32 + gk * 8);
#pragma unroll
  for (int i = 0; i < 8; ++i) {
    qf00[i] = (__bf16)((float)qf00[i] * 0.18033688f);
    qf01[i] = (__bf16)((float)qf01[i] * 0.18033688f);
    qf10[i] = (__bf16)((float)qf10[i] * 0.18033688f);
    qf11[i] = (__bf16)((float)qf11[i] * 0.18033688f);
  }

  const __bf16 one = (__bf16)1.0f;
  const bf16x8 vones = {one, one, one, one, one, one, one, one};
  const f32x4 vzero = {0.f, 0.f, 0.f, 0.f};
  f32x4 acco0[4], acco1[4];
  f32x4 asum0 = vzero, asum1 = vzero;      // rowsum in ACC layout (q=4gk+r)
  float mreg0 = -INFINITY, mreg1 = -INFINITY;
#pragma unroll
  for (int dt = 0; dt < 4; ++dt) { acco0[dt] = vzero; acco1[dt] = vzero; }

  // prologue: stage kt=0 into buf 0
#pragma unroll
  for (int j = 0; j < 2; ++j) {
    gload_lds16(kb + (size_t)j * 32 * QKVN + kSrc, &lK[0][j * 2048 + tid8]);
    gload_lds16(vb + (size_t)j * 32 * SEQ + vSrc, &lV[0][j * 2048 + tid8]);
  }
  int buf = 0;

  for (int kt = 0; kt < SEQ; kt += 64) {
    const bool haveNext = (kt + 64 < SEQ);
    __syncthreads();

    // masks FIRST (consumed this iter), staging SECOND (consumed next iter)
    float4 mk0[4], mk1[4];
#pragma unroll
    for (int j = 0; j < 4; ++j) {
      mk0[j] = *(const float4*)(mrow0 + kt + 16 * j);
      mk1[j] = *(const float4*)(mrow1 + kt + 16 * j);
    }
    __builtin_amdgcn_sched_barrier(0);

    if (haveNext) {
#pragma unroll
      for (int j = 0; j < 2; ++j) {
        gload_lds16(kb + (size_t)(kt + 64 + j * 32) * QKVN + kSrc, &lK[buf ^ 1][j * 2048 + tid8]);
        gload_lds16(vb + (kt + 64) + (size_t)j * 32 * SEQ + vSrc, &lV[buf ^ 1][j * 2048 + tid8]);
      }
    }

    // swapped QK^T for both tiles: each K-fragment read ONCE, used twice
    f32x4 s0[4], s1[4];
    __builtin_amdgcn_s_setprio(1);
#pragma unroll
    for (int j = 0; j < 4; ++j) {
      bf16x8 kfa = *(const bf16x8*)&lK[buf][j * 1024 + fr0];
      bf16x8 kfb = *(const bf16x8*)&lK[buf][j * 1024 + fr1];
      s0[j] = __builtin_amdgcn_mfma_f32_16x16x32_bf16(kfa, qf00, vzero, 0, 0, 0);
      s0[j] = __builtin_amdgcn_mfma_f32_16x16x32_bf16(kfb, qf01, s0[j], 0, 0, 0);
      s1[j] = __builtin_amdgcn_mfma_f32_16x16x32_bf16(kfa, qf10, vzero, 0, 0, 0);
      s1[j] = __builtin_amdgcn_mfma_f32_16x16x32_bf16(kfb, qf11, s1[j], 0, 0, 0);
    }
    __builtin_amdgcn_s_setprio(0);

    // masked log2-scores in place (two independent chains from here)
#pragma unroll
    for (int j = 0; j < 4; ++j) {
      const float* m0 = (const float*)&mk0[j];
      const float* m1 = (const float*)&mk1[j];
#pragma unroll
      for (int r = 0; r < 4; ++r) {
        s0[j][r] = fmaf(m0[r], -144269.50f, s0[j][r]);
        s1[j][r] = fmaf(m1[r], -144269.50f, s1[j][r]);
      }
    }

    // per-lane max (max3-shaped: 3-ary fmaxf nests fuse to v_max3_f32)
    float a0 = fmaxf(fmaxf(s0[0][0], s0[0][1]), s0[0][2]);
    float b0 = fmaxf(fmaxf(s0[0][3], s0[1][0]), s0[1][1]);
    float d0 = fmaxf(fmaxf(s0[1][2], s0[1][3]), s0[2][0]);
    float e0 = fmaxf(fmaxf(s0[2][1], s0[2][2]), s0[2][3]);
    float f0 = fmaxf(fmaxf(s0[3][0], s0[3][1]), s0[3][2]);
    float tm0 = fmaxf(fmaxf(fmaxf(a0, b0), d0), fmaxf(fmaxf(e0, f0), s0[3][3]));
    float a1 = fmaxf(fmaxf(s1[0][0], s1[0][1]), s1[0][2]);
    float b1 = fmaxf(fmaxf(s1[0][3], s1[1][0]), s1[1][1]);
    float d1 = fmaxf(fmaxf(s1[1][2], s1[1][3]), s1[2][0]);
    float e1 = fmaxf(fmaxf(s1[2][1], s1[2][2]), s1[2][3]);
    float f1 = fmaxf(fmaxf(s1[3][0], s1[3][1]), s1[3][2]);
    float tm1 = fmaxf(fmaxf(fmaxf(a1, b1), d1), fmaxf(fmaxf(e1, f1), s1[3][3]));
    tm0 = fmaxf(tm0, __shfl_xor(tm0, 16));
    tm1 = fmaxf(tm1, __shfl_xor(tm1, 16));
    tm0 = fmaxf(tm0, __shfl_xor(tm0, 32));
    tm1 = fmaxf(tm1, __shfl_xor(tm1, 32));

    // defer-rescale (T13, thr=8 in log2 domain), per tile
    if (__any(tm0 > mreg0 + 8.f)) {
      const float mn = fmaxf(mreg0, tm0);
      const float al = __builtin_amdgcn_exp2f(mreg0 - mn);
      mreg0 = mn;
      float alr[4];
#pragma unroll
      for (int r = 0; r < 4; ++r) alr[r] = __shfl(al, 20 * gk + r);
#pragma unroll
      for (int r = 0; r < 4; ++r) asum0[r] *= alr[r];
#pragma unroll
      for (int dt = 0; dt < 4; ++dt)
#pragma unroll
        for (int r = 0; r < 4; ++r) acco0[dt][r] *= alr[r];
    }
    if (__any(tm1 > mreg1 + 8.f)) {
      const float mn = fmaxf(mreg1, tm1);
      const float al = __builtin_amdgcn_exp2f(mreg1 - mn);
      mreg1 = mn;
      float alr[4];
#pragma unroll
      for (int r = 0; r < 4; ++r) alr[r] = __shfl(al, 20 * gk + r);
#pragma unroll
      for (int r = 0; r < 4; ++r) asum1[r] *= alr[r];
#pragma unroll
      for (int dt = 0; dt < 4; ++dt)
#pragma unroll
        for (int r = 0; r < 4; ++r) acco1[dt][r] *= alr[r];
    }

    // P = exp2(s - m) in place (rowsum handled by MFMA-ones below)
#pragma unroll
    for (int j = 0; j < 4; ++j)
#pragma unroll
      for (int r = 0; r < 4; ++r) {
        s0[j][r] = __builtin_amdgcn_exp2f(s0[j][r] - mreg0);
        s1[j][r] = __builtin_amdgcn_exp2f(s1[j][r] - mreg1);
      }

    // pack P -> A-fragments directly (k-slot permutation; no LDS round-trip)
    union { unsigned int u[8]; bf16x8 v[2]; } pu0, pu1;
#pragma unroll
    for (int j = 0; j < 4; ++j) {
      asm("v_cvt_pk_bf16_f32 %0, %1, %2" : "=v"(pu0.u[2 * j]) : "v"(s0[j][0]), "v"(s0[j][1]));
      asm("v_cvt_pk_bf16_f32 %0, %1, %2" : "=v"(pu0.u[2 * j + 1]) : "v"(s0[j][2]), "v"(s0[j][3]));
      asm("v_cvt_pk_bf16_f32 %0, %1, %2" : "=v"(pu1.u[2 * j]) : "v"(s1[j][0]), "v"(s1[j][1]));
      asm("v_cvt_pk_bf16_f32 %0, %1, %2" : "=v"(pu1.u[2 * j + 1]) : "v"(s1[j][2]), "v"(s1[j][3]));
    }

    // PV + MFMA-ones rowsum (asum emerges in acc layout q=4gk+r, all lanes)
    __builtin_amdgcn_s_setprio(1);
    asum0 = __builtin_amdgcn_mfma_f32_16x16x32_bf16(pu0.v[0], vones, asum0, 0, 0, 0);
    asum0 = __builtin_amdgcn_mfma_f32_16x16x32_bf16(pu0.v[1], vones, asum0, 0, 0, 0);
    asum1 = __builtin_amdgcn_mfma_f32_16x16x32_bf16(pu1.v[0], vones, asum1, 0, 0, 0);
    asum1 = __builtin_amdgcn_mfma_f32_16x16x32_bf16(pu1.v[1], vones, asum1, 0, 0, 0);
#pragma unroll
    for (int dt = 0; dt < 4; ++dt) {
      const unsigned short* vrow = &lV[buf][dt * 1024];
      bf16x4 a0v = *(const bf16x4*)(vrow + vg0);
      bf16x4 a1v = *(const bf16x4*)(vrow + vg1);
      bf16x4 a2v = *(const bf16x4*)(vrow + vg2);
      bf16x4 a3v = *(const bf16x4*)(vrow + vg3);
      bf16x8 vf0 = __builtin_shufflevector(a0v, a1v, 0, 1, 2, 3, 4, 5, 6, 7);
      bf16x8 vf1 = __builtin_shufflevector(a2v, a3v, 0, 1, 2, 3, 4, 5, 6, 7);
      acco0[dt] = __builtin_amdgcn_mfma_f32_16x16x32_bf16(pu0.v[0], vf0, acco0[dt], 0, 0, 0);
      acco0[dt] = __builtin_amdgcn_mfma_f32_16x16x32_bf16(pu0.v[1], vf1, acco0[dt], 0, 0, 0);
      acco1[dt] = __builtin_amdgcn_mfma_f32_16x16x32_bf16(pu1.v[0], vf0, acco1[dt], 0, 0, 0);
      acco1[dt] = __builtin_amdgcn_mfma_f32_16x16x32_bf16(pu1.v[1], vf1, acco1[dt], 0, 0, 0);
    }
    __builtin_amdgcn_s_setprio(0);
    buf ^= 1;
  }

  // normalize + store both tiles (asum already in acc layout: no shfl)
  float inv0[4], inv1[4];
#pragma unroll
  for (int r = 0; r < 4; ++r) {
    inv0[r] = 1.0f / asum0[r];
    inv1[r] = 1.0f / asum1[r];
  }
  unsigned short* ob0 = aout + (size_t)(b * SEQ + q0) * CDIM + h * HD;
  unsigned short* ob1 = ob0 + (size_t)64 * CDIM;
#pragma unroll
  for (int r = 0; r < 4; ++r)
#pragma unroll
    for (int dt = 0; dt < 4; ++dt) {
      ob0[(size_t)(4 * gk + r) * CDIM + dt * 16 + c] = f2bf(acco0[dt][r] * inv0[r]);
      ob1[(size_t)(4 * gk + r) * CDIM + dt * 16 + c] = f2bf(acco1[dt][r] * inv1[r]);
    }
}

extern "C" void kernel_launch(void* const* d_in, const int* in_sizes, int n_in,
                              void* d_out, int out_size, void* d_ws, size_t ws_size,
                              hipStream_t stream) {
  (void)in_sizes; (void)n_in; (void)out_size; (void)ws_size;
  const float* x      = (const float*)d_in[0];
  const float* mask   = (const float*)d_in[2];
  const float* qkv_w  = (const float*)d_in[3];
  const float* proj_w = (const float*)d_in[4];
  const float* proj_b = (const float*)d_in[5];
  float* out = (float*)d_out;
  char* ws = (char*)d_ws;

  unsigned short* xb    = (unsigned short*)(ws + 0);         // x bf16:      12,582,912
  unsigned short* wqb   = (unsigned short*)(ws + 12582912);  // qkv_w bf16:     884,736
  unsigned short* wpb   = (unsigned short*)(ws + 13467648);  // proj_w bf16:    294,912
  unsigned short* qkvb  = (unsigned short*)(ws + 13762560);  // qkv bf16:    37,748,736
  unsigned short* vtb   = (unsigned short*)(ws + 51511296);  // V^T bf16:    12,582,912
  unsigned short* aoutb = (unsigned short*)(ws + 64094208);  // attn out:    12,582,912

  k_convert3<<<6720, 256, 0, stream>>>(x, xb, qkv_w, wqb, proj_w, wpb);
  // QKV GEMM with fused V-transpose epilogue (k_vtrans eliminated)
  k_gemm_bt<0><<<dim3(128, 9), 256, 0, stream>>>(xb, wqb, qkvb, nullptr, vtb, nullptr, 16384, 1152, 384);
  k_attn<<<768, 256, 0, stream>>>(qkvb, mask, vtb, aoutb);
  k_gemm_bt<1><<<dim3(128, 3), 256, 0, stream>>>(aoutb, wpb, nullptr, out, nullptr, proj_b, 16384, 384, 384);
}